// Round 6
// baseline (437.576 us; speedup 1.0000x reference)
//
#include <hip/hip_runtime.h>
#include <hip/hip_fp16.h>

#define BN_EPS 1e-5f
#define CHUNK 4096            // edges per bucketing block (hist and scatter must match)
#define BBITS 7               // 128 nodes per bucket

typedef _Float16 half8 __attribute__((ext_vector_type(8)));
typedef float f32x4 __attribute__((ext_vector_type(4)));

__device__ __forceinline__ float4 f4zero() { return make_float4(0.f, 0.f, 0.f, 0.f); }

// ---------------- K1: packW(all 3) + bucket histogram + global degree counts ----------------

__global__ __launch_bounds__(256) void k_pack_hist(const float* __restrict__ W1,
                                                   const float* __restrict__ W2,
                                                   const float* __restrict__ W3,
                                                   _Float16* __restrict__ pW,
                                                   const int* __restrict__ dst,
                                                   int* __restrict__ tableT,
                                                   int* __restrict__ counts,
                                                   int nA, int nbuck, int e) {
    __shared__ int h[1024];
    int tid = threadIdx.x;
    if (blockIdx.x < 24) {            // W pre-pack: f32 [128][128] -> f16 B-fragment order
        int t = blockIdx.x * 256 + tid;   // 0..6143
        int wi = t >> 11;
        int tt = t & 2047;
        const float* W = (wi == 0) ? W1 : ((wi == 1) ? W2 : W3);
        int kc = tt >> 9;
        int rem = tt & 511;
        int ct = rem >> 6;
        int lane = rem & 63;
        int q = lane >> 4;
        int col = ct * 16 + (lane & 15);
        half8 hh;
#pragma unroll
        for (int j = 0; j < 8; ++j)
            hh[j] = (_Float16)W[(kc * 32 + q * 8 + j) * 128 + col];
        *(half8*)(pW + (size_t)t * 8) = hh;
        return;
    }
    int blk = blockIdx.x - 24;
    for (int k = tid; k < 1024; k += 256) h[k] = 0;
    __syncthreads();
    int base = blk * CHUNK;
    if (base + CHUNK <= e && (e & 3) == 0) {
        const int4* d4 = (const int4*)(dst + base);
#pragma unroll
        for (int t = 0; t < CHUNK / 1024; ++t) {
            int4 d = d4[t * 256 + tid];
            atomicAdd(&h[d.x >> BBITS], 1);
            atomicAdd(&h[d.y >> BBITS], 1);
            atomicAdd(&h[d.z >> BBITS], 1);
            atomicAdd(&h[d.w >> BBITS], 1);
            atomicAdd(&counts[d.x], 1);
            atomicAdd(&counts[d.y], 1);
            atomicAdd(&counts[d.z], 1);
            atomicAdd(&counts[d.w], 1);
        }
    } else {
        for (int i = base + tid; i < e && i < base + CHUNK; i += 256) {
            int d = dst[i];
            atomicAdd(&h[d >> BBITS], 1);
            atomicAdd(&counts[d], 1);
        }
    }
    __syncthreads();
    for (int k = tid; k < nbuck; k += 256)
        tableT[(size_t)k * nA + blk] = h[k];
}

// ---------------- K2/K3: 2-op exclusive scan of tableT (+ dinv from counts) ----------------

__global__ __launch_bounds__(1024) void k_scan_block(const int* __restrict__ in,
                                                     int* __restrict__ outp,
                                                     int* __restrict__ partials, int len) {
    __shared__ int s[1024];
    int t = threadIdx.x;
    int gid = blockIdx.x * 1024 + t;
    int v = (gid < len) ? in[gid] : 0;
    int x = v;
    s[t] = x;
    __syncthreads();
    for (int d = 1; d < 1024; d <<= 1) {
        int y = (t >= d) ? s[t - d] : 0;
        __syncthreads();
        x += y;
        s[t] = x;
        __syncthreads();
    }
    if (gid < len) outp[gid] = x - v;
    if (t == 1023) partials[blockIdx.x] = x;
}

// blocks [0,gT): add partials into tableT; blocks [gT,..): dinv = rsqrt(counts+1)
__global__ __launch_bounds__(256) void k_scan_addp_dinv(int* __restrict__ data,
                                                        const int* __restrict__ partials,
                                                        int len,
                                                        const int* __restrict__ counts,
                                                        float* __restrict__ dinv,
                                                        int n, int gT) {
    __shared__ int red[256];
    int tid = threadIdx.x;
    if ((int)blockIdx.x >= gT) {
        int node = ((int)blockIdx.x - gT) * 256 + tid;
        if (node < n) dinv[node] = rsqrtf((float)(counts[node] + 1));
        return;
    }
    int K = blockIdx.x >> 2;          // number of preceding 1024-segments
    int s = 0;
    for (int t = tid; t < K; t += 256) s += partials[t];
    red[tid] = s;
    __syncthreads();
    for (int d = 128; d > 0; d >>= 1) {
        if (tid < d) red[tid] += red[tid + d];
        __syncthreads();
    }
    int gid = blockIdx.x * 256 + tid;
    if (gid < len) data[gid] += red[0];
}

// ---------------- GEMM body (device): C[n,128](f16) = (A @ W) * dinv[row] ----------------

template <bool AF32>
__device__ __forceinline__ void gemm_body(int bid, int tid, char* smem,
                                          const void* __restrict__ Av,
                                          const _Float16* __restrict__ pW,
                                          const float* __restrict__ dinv,
                                          uint4* __restrict__ C, int n) {
    uint4* sW = (uint4*)smem;
    {
        const uint4* gW = (const uint4*)pW;
#pragma unroll
        for (int i = 0; i < 8; ++i) sW[tid + 256 * i] = gW[tid + 256 * i];
    }
    __syncthreads();

    int wave = tid >> 6, lane = tid & 63;
    int quad = lane >> 4, l16 = lane & 15;
    int row0 = bid * 64 + wave * 16;
    int arow = row0 + l16;
    int arowc = (arow < n) ? arow : (n - 1);

    half8 af[4];
    if (AF32) {
        const float* A = (const float*)Av + (size_t)arowc * 128 + quad * 8;
#pragma unroll
        for (int kc = 0; kc < 4; ++kc) {
            float4 lo = *(const float4*)(A + kc * 32);
            float4 hi = *(const float4*)(A + kc * 32 + 4);
            half8 h;
            h[0] = (_Float16)lo.x; h[1] = (_Float16)lo.y;
            h[2] = (_Float16)lo.z; h[3] = (_Float16)lo.w;
            h[4] = (_Float16)hi.x; h[5] = (_Float16)hi.y;
            h[6] = (_Float16)hi.z; h[7] = (_Float16)hi.w;
            af[kc] = h;
        }
    } else {
        const _Float16* A = (const _Float16*)Av + (size_t)arowc * 128 + quad * 8;
#pragma unroll
        for (int kc = 0; kc < 4; ++kc)
            af[kc] = *(const half8*)(A + kc * 32);
    }

    f32x4 acc[8];
#pragma unroll
    for (int ct = 0; ct < 8; ++ct) acc[ct] = (f32x4){0.f, 0.f, 0.f, 0.f};

#pragma unroll
    for (int kc = 0; kc < 4; ++kc) {
#pragma unroll
        for (int ct = 0; ct < 8; ++ct) {
            half8 bf = *(half8*)&sW[(kc * 8 + ct) * 64 + lane];
            acc[ct] = __builtin_amdgcn_mfma_f32_16x16x32_f16(af[kc], bf, acc[ct], 0, 0, 0);
        }
    }

    __syncthreads();

    _Float16* eb = (_Float16*)smem + wave * 16 * 136;   // 136 halfs = 272 B row stride
    float dv[4];
#pragma unroll
    for (int r = 0; r < 4; ++r) {
        int rr = row0 + quad * 4 + r;
        dv[r] = dinv[(rr < n) ? rr : (n - 1)];
    }
#pragma unroll
    for (int ct = 0; ct < 8; ++ct)
#pragma unroll
        for (int r = 0; r < 4; ++r)
            eb[(quad * 4 + r) * 136 + ct * 16 + l16] = (_Float16)(acc[ct][r] * dv[r]);

#pragma unroll
    for (int i = 0; i < 4; ++i) {
        int linear = i * 64 + lane;
        int r = linear >> 4, c = linear & 15;
        uint4 v = *(uint4*)((char*)eb + r * 272 + c * 16);
        int row = row0 + r;
        if (row < n) C[(size_t)row * 16 + c] = v;
    }
}

__global__ __launch_bounds__(256) void k_gemm_mfma(const void* __restrict__ Av,
                                                   const _Float16* __restrict__ pW,
                                                   const float* __restrict__ dinv,
                                                   uint4* __restrict__ C, int n) {
    __shared__ char smem[32768];
    gemm_body<false>(blockIdx.x, threadIdx.x, smem, Av, pW, dinv, C, n);
}

// ---------------- K4: bucket-grouped COO scatter (LDS cursors) + layer-1 GEMM ----------------
// blocks [0,nA): scatter edges into bed; blocks [nA,..): GEMM1 from f32 x (needs dinv only)

__global__ __launch_bounds__(256) void k_scatter_gemm(const int* __restrict__ src,
                                                      const int* __restrict__ dst,
                                                      const int* __restrict__ tableT,
                                                      int2* __restrict__ bed,
                                                      int nA, int nbuck, int e,
                                                      const float* __restrict__ x,
                                                      const _Float16* __restrict__ pW,
                                                      const float* __restrict__ dinv,
                                                      uint4* __restrict__ C, int n) {
    __shared__ char smem[32768];
    int tid = threadIdx.x;
    if ((int)blockIdx.x >= nA) {
        gemm_body<true>((int)blockIdx.x - nA, tid, smem, x, pW, dinv, C, n);
        return;
    }
    int* cur = (int*)smem;
    int blk = blockIdx.x;
    for (int k = tid; k < nbuck; k += 256)
        cur[k] = tableT[(size_t)k * nA + blk];
    __syncthreads();
    int base = blk * CHUNK;
    if (base + CHUNK <= e && (e & 3) == 0) {
        const int4* s4 = (const int4*)(src + base);
        const int4* d4 = (const int4*)(dst + base);
#pragma unroll
        for (int t = 0; t < CHUNK / 1024; ++t) {
            int4 s = s4[t * 256 + tid];
            int4 d = d4[t * 256 + tid];
            int p0 = atomicAdd(&cur[d.x >> BBITS], 1); bed[p0] = make_int2(s.x, d.x);
            int p1 = atomicAdd(&cur[d.y >> BBITS], 1); bed[p1] = make_int2(s.y, d.y);
            int p2 = atomicAdd(&cur[d.z >> BBITS], 1); bed[p2] = make_int2(s.z, d.z);
            int p3 = atomicAdd(&cur[d.w >> BBITS], 1); bed[p3] = make_int2(s.w, d.w);
        }
    } else {
        for (int i = base + tid; i < e && i < base + CHUNK; i += 256) {
            int d = dst[i];
            int p = atomicAdd(&cur[d >> BBITS], 1);
            bed[p] = make_int2(src[i], d);
        }
    }
}

// ---------------- K5: fused per-bucket rank + offsets + pad-fill + er place ----------------
// er base for bucket b = bedStart[b] + 1024*b (per-bucket pad slack <= 128*7 < 1024).
// offs2[node] = {start, end} (end - start = padded degree). er stores BYTE offsets (src*256).

__global__ __launch_bounds__(256) void k_rank_finalize(const int2* __restrict__ bed,
                                                       const int* __restrict__ tableT,
                                                       int2* __restrict__ offs2,
                                                       int* __restrict__ er,
                                                       unsigned int* __restrict__ bufAzero,
                                                       int nA, int nbuck, int n, int e) {
    __shared__ int lcnt[128];
    __shared__ int lscan[128];
    __shared__ int loff[128];
    int b = blockIdx.x, tid = threadIdx.x;
    if (tid < 128) lcnt[tid] = 0;
    __syncthreads();
    int start = tableT[(size_t)b * nA];
    int end = (b + 1 < nbuck) ? tableT[(size_t)(b + 1) * nA] : e;
    // pass 1: per-node counts
    for (int i = start + tid; i < end; i += 256)
        atomicAdd(&lcnt[bed[i].y & 127], 1);
    __syncthreads();
    int padded = 0;
    if (tid < 128) {
        padded = (lcnt[tid] + 7) & ~7;
        lscan[tid] = padded;
    }
    __syncthreads();
    for (int d = 1; d < 128; d <<= 1) {          // Hillis-Steele inclusive scan over 128
        int y = (tid < 128 && tid >= d) ? lscan[tid - d] : 0;
        __syncthreads();
        if (tid < 128) lscan[tid] += y;
        __syncthreads();
    }
    int ebase = start + (b << 10);
    if (tid < 128) {
        loff[tid] = lscan[tid] - padded;          // exclusive padded offset within bucket
        int node = (b << BBITS) + tid;
        if (node < n) {
            int c = lcnt[tid];
            int o = ebase + loff[tid];
            offs2[node] = make_int2(o, o + padded);
            for (int j = c; j < padded; ++j) er[o + j] = n << 8;   // dummy zero-row
        }
    }
    if (b == 0 && tid < 64) bufAzero[tid] = 0u;   // zero 256 B pad row of bufA
    __syncthreads();
    if (tid < 128) lcnt[tid] = 0;                 // reuse as rank cursors
    __syncthreads();
    // pass 2: place (bed re-read is L2-hot)
    for (int i = start + tid; i < end; i += 256) {
        int2 q = bed[i];
        int l = q.y & 127;
        int r = atomicAdd(&lcnt[l], 1);
        er[ebase + loff[l] + r] = q.x << 8;
    }
}

// ---------------- fma_mix accumulate: acc += (f32)h16, 1 instr per element ----------------
// uint4 = 8 halfs: q.x -> f0,f1 | q.y -> f2,f3 | q.z -> f4,f5 | q.w -> f6,f7

__device__ __forceinline__ void acc_row4(float4& aL, float4& aH, uint4 q) {
    asm("v_fma_mix_f32 %0, %1, 1.0, %0 op_sel:[0,0,0] op_sel_hi:[1,0,0]" : "+v"(aL.x) : "v"(q.x));
    asm("v_fma_mix_f32 %0, %1, 1.0, %0 op_sel:[1,0,0] op_sel_hi:[1,0,0]" : "+v"(aL.y) : "v"(q.x));
    asm("v_fma_mix_f32 %0, %1, 1.0, %0 op_sel:[0,0,0] op_sel_hi:[1,0,0]" : "+v"(aL.z) : "v"(q.y));
    asm("v_fma_mix_f32 %0, %1, 1.0, %0 op_sel:[1,0,0] op_sel_hi:[1,0,0]" : "+v"(aL.w) : "v"(q.y));
    asm("v_fma_mix_f32 %0, %1, 1.0, %0 op_sel:[0,0,0] op_sel_hi:[1,0,0]" : "+v"(aH.x) : "v"(q.z));
    asm("v_fma_mix_f32 %0, %1, 1.0, %0 op_sel:[1,0,0] op_sel_hi:[1,0,0]" : "+v"(aH.y) : "v"(q.z));
    asm("v_fma_mix_f32 %0, %1, 1.0, %0 op_sel:[0,0,0] op_sel_hi:[1,0,0]" : "+v"(aH.z) : "v"(q.w));
    asm("v_fma_mix_f32 %0, %1, 1.0, %0 op_sel:[1,0,0] op_sel_hi:[1,0,0]" : "+v"(aH.w) : "v"(q.w));
}

// ---------------- CSR aggregation + bias + ReLU + BN (+ optional classifier) ----------------
// 16 lanes/node, uint4 gathers (round-5 verified). offs2 = {start, end} per node.

template <bool FUSE_CLS>
__global__ __launch_bounds__(256) void k_aggregate(const uint4* __restrict__ Ah,
                                                   const int2* __restrict__ offs2,
                                                   const int* __restrict__ er,
                                                   const float* __restrict__ dinv,
                                                   const float* __restrict__ bias,
                                                   const float* __restrict__ g,
                                                   const float* __restrict__ be,
                                                   const float* __restrict__ rm,
                                                   const float* __restrict__ rv,
                                                   uint4* __restrict__ Hout,
                                                   const float* __restrict__ Wc,
                                                   const float* __restrict__ bc,
                                                   float* __restrict__ out, int n) {
    int lane = threadIdx.x & 15;
    int node = blockIdx.x * 16 + (threadIdx.x >> 4);
    if (node >= n) return;

    const char* AhB = (const char*)Ah;
    unsigned int l16 = (unsigned int)lane * 16u;

    float4 aL = f4zero(), aH = f4zero();
    // self loop (weight folds to dinv^2); 32-bit offset addressing
    acc_row4(aL, aH, *(const uint4*)(AhB + (((unsigned int)node << 8) + l16)));

    int2 offc = offs2[node];
    int e0 = offc.x, e1 = offc.y;
    for (int e = e0; e < e1; e += 8) {
        int4 ra = *(const int4*)(er + e);
        int4 rb = *(const int4*)(er + e + 4);
        uint4 v0 = *(const uint4*)(AhB + ((unsigned int)ra.x + l16));
        uint4 v1 = *(const uint4*)(AhB + ((unsigned int)ra.y + l16));
        uint4 v2 = *(const uint4*)(AhB + ((unsigned int)ra.z + l16));
        uint4 v3 = *(const uint4*)(AhB + ((unsigned int)ra.w + l16));
        uint4 v4 = *(const uint4*)(AhB + ((unsigned int)rb.x + l16));
        uint4 v5 = *(const uint4*)(AhB + ((unsigned int)rb.y + l16));
        uint4 v6 = *(const uint4*)(AhB + ((unsigned int)rb.z + l16));
        uint4 v7 = *(const uint4*)(AhB + ((unsigned int)rb.w + l16));
        acc_row4(aL, aH, v0); acc_row4(aL, aH, v1); acc_row4(aL, aH, v2); acc_row4(aL, aH, v3);
        acc_row4(aL, aH, v4); acc_row4(aL, aH, v5); acc_row4(aL, aH, v6); acc_row4(aL, aH, v7);
    }

    float di = dinv[node];
    aL.x *= di; aL.y *= di; aL.z *= di; aL.w *= di;
    aH.x *= di; aH.y *= di; aH.z *= di; aH.w *= di;

    // lane covers features [8*lane, 8*lane+8) -> float4 indices 2*lane, 2*lane+1
    float4 bL  = ((const float4*)bias)[2 * lane], bH  = ((const float4*)bias)[2 * lane + 1];
    float4 gL  = ((const float4*)g)[2 * lane],    gH  = ((const float4*)g)[2 * lane + 1];
    float4 beL = ((const float4*)be)[2 * lane],   beH = ((const float4*)be)[2 * lane + 1];
    float4 rmL = ((const float4*)rm)[2 * lane],   rmH = ((const float4*)rm)[2 * lane + 1];
    float4 rvL = ((const float4*)rv)[2 * lane],   rvH = ((const float4*)rv)[2 * lane + 1];

    float4 oL, oH;
    float v;
    v = fmaxf(aL.x + bL.x, 0.f); oL.x = (v - rmL.x) * rsqrtf(rvL.x + BN_EPS) * gL.x + beL.x;
    v = fmaxf(aL.y + bL.y, 0.f); oL.y = (v - rmL.y) * rsqrtf(rvL.y + BN_EPS) * gL.y + beL.y;
    v = fmaxf(aL.z + bL.z, 0.f); oL.z = (v - rmL.z) * rsqrtf(rvL.z + BN_EPS) * gL.z + beL.z;
    v = fmaxf(aL.w + bL.w, 0.f); oL.w = (v - rmL.w) * rsqrtf(rvL.w + BN_EPS) * gL.w + beL.w;
    v = fmaxf(aH.x + bH.x, 0.f); oH.x = (v - rmH.x) * rsqrtf(rvH.x + BN_EPS) * gH.x + beH.x;
    v = fmaxf(aH.y + bH.y, 0.f); oH.y = (v - rmH.y) * rsqrtf(rvH.y + BN_EPS) * gH.y + beH.y;
    v = fmaxf(aH.z + bH.z, 0.f); oH.z = (v - rmH.z) * rsqrtf(rvH.z + BN_EPS) * gH.z + beH.z;
    v = fmaxf(aH.w + bH.w, 0.f); oH.w = (v - rmH.w) * rsqrtf(rvH.w + BN_EPS) * gH.w + beH.w;

    if (!FUSE_CLS) {
        __half2 p0 = __floats2half2_rn(oL.x, oL.y);
        __half2 p1 = __floats2half2_rn(oL.z, oL.w);
        __half2 p2 = __floats2half2_rn(oH.x, oH.y);
        __half2 p3 = __floats2half2_rn(oH.z, oH.w);
        uint4 u;
        u.x = *(unsigned int*)&p0;
        u.y = *(unsigned int*)&p1;
        u.z = *(unsigned int*)&p2;
        u.w = *(unsigned int*)&p3;
        Hout[(size_t)node * 16 + lane] = u;
    } else {
        const float4* Wv = (const float4*)Wc;   // Wc[f][2]: float4 i = features 2i,2i+1
        float4 w0 = Wv[4 * lane];
        float4 w1 = Wv[4 * lane + 1];
        float4 w2 = Wv[4 * lane + 2];
        float4 w3 = Wv[4 * lane + 3];
        float p0 = oL.x * w0.x + oL.y * w0.z + oL.z * w1.x + oL.w * w1.z
                 + oH.x * w2.x + oH.y * w2.z + oH.z * w3.x + oH.w * w3.z;
        float p1 = oL.x * w0.y + oL.y * w0.w + oL.z * w1.y + oL.w * w1.w
                 + oH.x * w2.y + oH.y * w2.w + oH.z * w3.y + oH.w * w3.w;
#pragma unroll
        for (int d = 8; d >= 1; d >>= 1) {
            p0 += __shfl_down(p0, d, 16);
            p1 += __shfl_down(p1, d, 16);
        }
        if (lane == 0) {
            out[node * 2 + 0] = p0 + bc[0];
            out[node * 2 + 1] = p1 + bc[1];
        }
    }
}

// ---------------- launch ----------------

extern "C" void kernel_launch(void* const* d_in, const int* in_sizes, int n_in,
                              void* d_out, int out_size, void* d_ws, size_t ws_size,
                              hipStream_t stream) {
    const float* x   = (const float*)d_in[0];
    const int*   ei  = (const int*)d_in[1];
    const float* W1  = (const float*)d_in[2];
    const float* b1  = (const float*)d_in[3];
    const float* W2  = (const float*)d_in[4];
    const float* b2  = (const float*)d_in[5];
    const float* W3  = (const float*)d_in[6];
    const float* b3  = (const float*)d_in[7];
    const float* g1  = (const float*)d_in[8];
    const float* be1 = (const float*)d_in[9];
    const float* rm1 = (const float*)d_in[10];
    const float* rv1 = (const float*)d_in[11];
    const float* g2  = (const float*)d_in[12];
    const float* be2 = (const float*)d_in[13];
    const float* rm2 = (const float*)d_in[14];
    const float* rv2 = (const float*)d_in[15];
    const float* g3  = (const float*)d_in[16];
    const float* be3 = (const float*)d_in[17];
    const float* rm3 = (const float*)d_in[18];
    const float* rv3 = (const float*)d_in[19];
    const float* Wc  = (const float*)d_in[20];
    const float* bc  = (const float*)d_in[21];
    float* out = (float*)d_out;

    int n = in_sizes[0] / 128;
    int e = in_sizes[1] / 2;
    const int* src = ei;
    const int* dst = ei + e;

    char* ws = (char*)d_ws;
    size_t off = 0;
    auto alloc = [&](size_t bytes) -> char* {
        char* p = ws + off;
        off += (bytes + 255) & ~(size_t)255;
        return p;
    };
    int nA    = (e + CHUNK - 1) / CHUNK;
    int nbuck = (n + (1 << BBITS) - 1) >> BBITS;
    int tlen  = nbuck * nA;
    int erCap = e + (nbuck << 10) + 64;

    char*      bufA     = (char*) alloc((size_t)(n + 1) * 256);   // GEMM out f16 [n+1][128]
    char*      bufH     = (char*) alloc((size_t)n * 256);         // H f16; bed aliases this
    float*     dinv     = (float*)alloc((size_t)n * 4);
    int*       counts   = (int*)  alloc((size_t)n * 4);
    int2*      offs2    = (int2*) alloc((size_t)n * 8);
    int*       tableT   = (int*)  alloc((size_t)(tlen + 1) * 4);
    int*       parts    = (int*)  alloc(8192);
    int*       er       = (int*)  alloc((size_t)erCap * 4);
    _Float16*  pW       = (_Float16*)alloc(3 * 16384 * 2);
    (void)ws_size; (void)n_in; (void)out_size;

    // bed aliases bufH (dead until first aggregate; consumed by k_rank_finalize)
    int2* bed = (int2*)bufH;                         // e*8 = 12.8 MB < 25.6 MB

    int nbT   = (tlen + 1023) / 1024;
    int gT    = (tlen + 255) / 256;
    int gD    = (n + 255) / 256;
    int gGemm = (n + 63) / 64;
    int gAgg  = (n + 15) / 16;

    hipMemsetAsync(counts, 0, (size_t)n * 4, stream);
    k_pack_hist<<<24 + nA, 256, 0, stream>>>(W1, W2, W3, pW, dst, tableT, counts,
                                             nA, nbuck, e);
    k_scan_block<<<nbT, 1024, 0, stream>>>(tableT, tableT, parts, tlen);
    k_scan_addp_dinv<<<gT + gD, 256, 0, stream>>>(tableT, parts, tlen, counts, dinv, n, gT);
    // scatter (nA blocks) + layer-1 GEMM (needs only dinv + x) in one launch
    k_scatter_gemm<<<nA + gGemm, 256, 0, stream>>>(src, dst, tableT, bed, nA, nbuck, e,
                                                   x, pW, dinv, (uint4*)bufA, n);
    k_rank_finalize<<<nbuck, 256, 0, stream>>>(bed, tableT, offs2, er,
                                               (unsigned int*)(bufA + (size_t)n * 256),
                                               nA, nbuck, n, e);

    // layer 1 aggregate (bufA -> bufH)
    k_aggregate<false><<<gAgg, 256, 0, stream>>>((const uint4*)bufA, offs2, er, dinv,
                                                 b1, g1, be1, rm1, rv1, (uint4*)bufH,
                                                 nullptr, nullptr, nullptr, n);
    // layer 2 GEMM (bufH -> bufA), aggregate (bufA -> bufH)
    k_gemm_mfma<<<gGemm, 256, 0, stream>>>(bufH, pW + 16384, dinv, (uint4*)bufA, n);
    k_aggregate<false><<<gAgg, 256, 0, stream>>>((const uint4*)bufA, offs2, er, dinv,
                                                 b2, g2, be2, rm2, rv2, (uint4*)bufH,
                                                 nullptr, nullptr, nullptr, n);
    // layer 3 GEMM (bufH -> bufA), aggregate + classifier (bufA -> out)
    k_gemm_mfma<<<gGemm, 256, 0, stream>>>(bufH, pW + 32768, dinv, (uint4*)bufA, n);
    k_aggregate<true><<<gAgg, 256, 0, stream>>>((const uint4*)bufA, offs2, er, dinv,
                                                b3, g3, be3, rm3, rv3, nullptr,
                                                Wc, bc, out, n);
}

// Round 7
// 390.320 us; speedup vs baseline: 1.1211x; 1.1211x over previous
//
#include <hip/hip_runtime.h>
#include <hip/hip_fp16.h>

#define BN_EPS 1e-5f
#define CHUNK 4096            // edges per bucketing block (hist and scatter must match)
#define BBITS 7               // 128 nodes per bucket

typedef _Float16 half8 __attribute__((ext_vector_type(8)));
typedef float f32x4 __attribute__((ext_vector_type(4)));

__device__ __forceinline__ float4 f4zero() { return make_float4(0.f, 0.f, 0.f, 0.f); }

// ---------------- K1: packW(all 3) + bucket histogram (LDS atomics only) ----------------

__global__ __launch_bounds__(256) void k_pack_hist(const float* __restrict__ W1,
                                                   const float* __restrict__ W2,
                                                   const float* __restrict__ W3,
                                                   _Float16* __restrict__ pW,
                                                   const int* __restrict__ dst,
                                                   int* __restrict__ tableT,
                                                   int nA, int nbuck, int e) {
    __shared__ int h[1024];
    int tid = threadIdx.x;
    if (blockIdx.x < 24) {            // W pre-pack: f32 [128][128] -> f16 B-fragment order
        int t = blockIdx.x * 256 + tid;   // 0..6143
        int wi = t >> 11;
        int tt = t & 2047;
        const float* W = (wi == 0) ? W1 : ((wi == 1) ? W2 : W3);
        int kc = tt >> 9;
        int rem = tt & 511;
        int ct = rem >> 6;
        int lane = rem & 63;
        int q = lane >> 4;
        int col = ct * 16 + (lane & 15);
        half8 hh;
#pragma unroll
        for (int j = 0; j < 8; ++j)
            hh[j] = (_Float16)W[(kc * 32 + q * 8 + j) * 128 + col];
        *(half8*)(pW + (size_t)t * 8) = hh;
        return;
    }
    int blk = blockIdx.x - 24;
    for (int k = tid; k < 1024; k += 256) h[k] = 0;
    __syncthreads();
    int base = blk * CHUNK;
    if (base + CHUNK <= e && (e & 3) == 0) {
        const int4* d4 = (const int4*)(dst + base);
#pragma unroll
        for (int t = 0; t < CHUNK / 1024; ++t) {
            int4 d = d4[t * 256 + tid];
            atomicAdd(&h[d.x >> BBITS], 1);
            atomicAdd(&h[d.y >> BBITS], 1);
            atomicAdd(&h[d.z >> BBITS], 1);
            atomicAdd(&h[d.w >> BBITS], 1);
        }
    } else {
        for (int i = base + tid; i < e && i < base + CHUNK; i += 256)
            atomicAdd(&h[dst[i] >> BBITS], 1);
    }
    __syncthreads();
    for (int k = tid; k < nbuck; k += 256)
        tableT[(size_t)k * nA + blk] = h[k];
}

// ---------------- K2/K3: 2-op exclusive scan of tableT ----------------

__global__ __launch_bounds__(1024) void k_scan_block(const int* __restrict__ in,
                                                     int* __restrict__ outp,
                                                     int* __restrict__ partials, int len) {
    __shared__ int s[1024];
    int t = threadIdx.x;
    int gid = blockIdx.x * 1024 + t;
    int v = (gid < len) ? in[gid] : 0;
    int x = v;
    s[t] = x;
    __syncthreads();
    for (int d = 1; d < 1024; d <<= 1) {
        int y = (t >= d) ? s[t - d] : 0;
        __syncthreads();
        x += y;
        s[t] = x;
        __syncthreads();
    }
    if (gid < len) outp[gid] = x - v;
    if (t == 1023) partials[blockIdx.x] = x;
}

// each 256-block self-sums the partials it needs
__global__ __launch_bounds__(256) void k_scan_addp(int* __restrict__ data,
                                                   const int* __restrict__ partials, int len) {
    __shared__ int red[256];
    int tid = threadIdx.x;
    int K = blockIdx.x >> 2;          // number of preceding 1024-segments
    int s = 0;
    for (int t = tid; t < K; t += 256) s += partials[t];
    red[tid] = s;
    __syncthreads();
    for (int d = 128; d > 0; d >>= 1) {
        if (tid < d) red[tid] += red[tid + d];
        __syncthreads();
    }
    int gid = blockIdx.x * 256 + tid;
    if (gid < len) data[gid] += red[0];
}

// ---------------- GEMM body (device): C[n,128](f16) = A @ W  (NO dinv scaling) ----------------

template <bool AF32>
__device__ __forceinline__ void gemm_body(int bid, int tid, char* smem,
                                          const void* __restrict__ Av,
                                          const _Float16* __restrict__ pW,
                                          uint4* __restrict__ C, int n) {
    uint4* sW = (uint4*)smem;
    {
        const uint4* gW = (const uint4*)pW;
#pragma unroll
        for (int i = 0; i < 8; ++i) sW[tid + 256 * i] = gW[tid + 256 * i];
    }
    __syncthreads();

    int wave = tid >> 6, lane = tid & 63;
    int quad = lane >> 4, l16 = lane & 15;
    int row0 = bid * 64 + wave * 16;
    int arow = row0 + l16;
    int arowc = (arow < n) ? arow : (n - 1);

    half8 af[4];
    if (AF32) {
        const float* A = (const float*)Av + (size_t)arowc * 128 + quad * 8;
#pragma unroll
        for (int kc = 0; kc < 4; ++kc) {
            float4 lo = *(const float4*)(A + kc * 32);
            float4 hi = *(const float4*)(A + kc * 32 + 4);
            half8 h;
            h[0] = (_Float16)lo.x; h[1] = (_Float16)lo.y;
            h[2] = (_Float16)lo.z; h[3] = (_Float16)lo.w;
            h[4] = (_Float16)hi.x; h[5] = (_Float16)hi.y;
            h[6] = (_Float16)hi.z; h[7] = (_Float16)hi.w;
            af[kc] = h;
        }
    } else {
        const _Float16* A = (const _Float16*)Av + (size_t)arowc * 128 + quad * 8;
#pragma unroll
        for (int kc = 0; kc < 4; ++kc)
            af[kc] = *(const half8*)(A + kc * 32);
    }

    f32x4 acc[8];
#pragma unroll
    for (int ct = 0; ct < 8; ++ct) acc[ct] = (f32x4){0.f, 0.f, 0.f, 0.f};

#pragma unroll
    for (int kc = 0; kc < 4; ++kc) {
#pragma unroll
        for (int ct = 0; ct < 8; ++ct) {
            half8 bf = *(half8*)&sW[(kc * 8 + ct) * 64 + lane];
            acc[ct] = __builtin_amdgcn_mfma_f32_16x16x32_f16(af[kc], bf, acc[ct], 0, 0, 0);
        }
    }

    __syncthreads();

    _Float16* eb = (_Float16*)smem + wave * 16 * 136;   // 136 halfs = 272 B row stride
#pragma unroll
    for (int ct = 0; ct < 8; ++ct)
#pragma unroll
        for (int r = 0; r < 4; ++r)
            eb[(quad * 4 + r) * 136 + ct * 16 + l16] = (_Float16)(acc[ct][r]);

#pragma unroll
    for (int i = 0; i < 4; ++i) {
        int linear = i * 64 + lane;
        int r = linear >> 4, c = linear & 15;
        uint4 v = *(uint4*)((char*)eb + r * 272 + c * 16);
        int row = row0 + r;
        if (row < n) C[(size_t)row * 16 + c] = v;
    }
}

__global__ __launch_bounds__(256) void k_gemm_mfma(const void* __restrict__ Av,
                                                   const _Float16* __restrict__ pW,
                                                   uint4* __restrict__ C, int n) {
    __shared__ char smem[32768];
    gemm_body<false>(blockIdx.x, threadIdx.x, smem, Av, pW, C, n);
}

// ---------------- K4: bucket-grouped COO scatter (LDS cursors) + layer-1 GEMM ----------------
// blocks [0,nA): scatter edges into bed; blocks [nA,..): GEMM1 from f32 x (dinv-free now)

__global__ __launch_bounds__(256) void k_scatter_gemm(const int* __restrict__ src,
                                                      const int* __restrict__ dst,
                                                      const int* __restrict__ tableT,
                                                      int2* __restrict__ bed,
                                                      int nA, int nbuck, int e,
                                                      const float* __restrict__ x,
                                                      const _Float16* __restrict__ pW,
                                                      uint4* __restrict__ C, int n) {
    __shared__ char smem[32768];
    int tid = threadIdx.x;
    if ((int)blockIdx.x >= nA) {
        gemm_body<true>((int)blockIdx.x - nA, tid, smem, x, pW, C, n);
        return;
    }
    int* cur = (int*)smem;
    int blk = blockIdx.x;
    for (int k = tid; k < nbuck; k += 256)
        cur[k] = tableT[(size_t)k * nA + blk];
    __syncthreads();
    int base = blk * CHUNK;
    if (base + CHUNK <= e && (e & 3) == 0) {
        const int4* s4 = (const int4*)(src + base);
        const int4* d4 = (const int4*)(dst + base);
#pragma unroll
        for (int t = 0; t < CHUNK / 1024; ++t) {
            int4 s = s4[t * 256 + tid];
            int4 d = d4[t * 256 + tid];
            int p0 = atomicAdd(&cur[d.x >> BBITS], 1); bed[p0] = make_int2(s.x, d.x);
            int p1 = atomicAdd(&cur[d.y >> BBITS], 1); bed[p1] = make_int2(s.y, d.y);
            int p2 = atomicAdd(&cur[d.z >> BBITS], 1); bed[p2] = make_int2(s.z, d.z);
            int p3 = atomicAdd(&cur[d.w >> BBITS], 1); bed[p3] = make_int2(s.w, d.w);
        }
    } else {
        for (int i = base + tid; i < e && i < base + CHUNK; i += 256) {
            int d = dst[i];
            int p = atomicAdd(&cur[d >> BBITS], 1);
            bed[p] = make_int2(src[i], d);
        }
    }
}

// ---------------- K5: fused per-bucket rank + dinv + offsets + pad-fill + er place ----------
// er base for bucket b = bedStart[b] + 1024*b (per-bucket pad slack <= 128*7 < 1024).
// offs2[node] = {start, end}; er stores BYTE offsets (src*256). dinv computed here (free).

__global__ __launch_bounds__(256) void k_rank_finalize(const int2* __restrict__ bed,
                                                       const int* __restrict__ tableT,
                                                       int2* __restrict__ offs2,
                                                       int* __restrict__ er,
                                                       float* __restrict__ dinv,
                                                       unsigned int* __restrict__ bufAzero,
                                                       int nA, int nbuck, int n, int e) {
    __shared__ int lcnt[128];
    __shared__ int lscan[128];
    __shared__ int loff[128];
    int b = blockIdx.x, tid = threadIdx.x;
    if (tid < 128) lcnt[tid] = 0;
    __syncthreads();
    int start = tableT[(size_t)b * nA];
    int end = (b + 1 < nbuck) ? tableT[(size_t)(b + 1) * nA] : e;
    // pass 1: per-node counts
    for (int i = start + tid; i < end; i += 256)
        atomicAdd(&lcnt[bed[i].y & 127], 1);
    __syncthreads();
    int padded = 0;
    if (tid < 128) {
        padded = (lcnt[tid] + 7) & ~7;
        lscan[tid] = padded;
    }
    __syncthreads();
    for (int d = 1; d < 128; d <<= 1) {          // Hillis-Steele inclusive scan over 128
        int y = (tid < 128 && tid >= d) ? lscan[tid - d] : 0;
        __syncthreads();
        if (tid < 128) lscan[tid] += y;
        __syncthreads();
    }
    int ebase = start + (b << 10);
    if (tid < 128) {
        loff[tid] = lscan[tid] - padded;          // exclusive padded offset within bucket
        int node = (b << BBITS) + tid;
        if (node < n) {
            int c = lcnt[tid];
            int o = ebase + loff[tid];
            offs2[node] = make_int2(o, o + padded);
            dinv[node] = rsqrtf((float)(c + 1));
            for (int j = c; j < padded; ++j) er[o + j] = n << 8;   // dummy zero-row
        }
    }
    if (b == 0 && tid < 64) bufAzero[tid] = 0u;   // zero 256 B pad row of bufA
    if (b == 0 && tid == 0) dinv[n] = 0.f;        // dummy-row scale (layer-1 path)
    __syncthreads();
    if (tid < 128) lcnt[tid] = 0;                 // reuse as rank cursors
    __syncthreads();
    // pass 2: place (bed re-read is L2-hot)
    for (int i = start + tid; i < end; i += 256) {
        int2 q = bed[i];
        int l = q.y & 127;
        int r = atomicAdd(&lcnt[l], 1);
        er[ebase + loff[l] + r] = q.x << 8;
    }
}

// ---------------- fma_mix accumulate ----------------
// uint4 = 8 halfs: q.x -> f0,f1 | q.y -> f2,f3 | q.z -> f4,f5 | q.w -> f6,f7
// plain: acc += (f32)h16           scaled: acc += (f32)h16 * s   (same instruction count)

__device__ __forceinline__ void acc_row4(float4& aL, float4& aH, uint4 q) {
    asm("v_fma_mix_f32 %0, %1, 1.0, %0 op_sel:[0,0,0] op_sel_hi:[1,0,0]" : "+v"(aL.x) : "v"(q.x));
    asm("v_fma_mix_f32 %0, %1, 1.0, %0 op_sel:[1,0,0] op_sel_hi:[1,0,0]" : "+v"(aL.y) : "v"(q.x));
    asm("v_fma_mix_f32 %0, %1, 1.0, %0 op_sel:[0,0,0] op_sel_hi:[1,0,0]" : "+v"(aL.z) : "v"(q.y));
    asm("v_fma_mix_f32 %0, %1, 1.0, %0 op_sel:[1,0,0] op_sel_hi:[1,0,0]" : "+v"(aL.w) : "v"(q.y));
    asm("v_fma_mix_f32 %0, %1, 1.0, %0 op_sel:[0,0,0] op_sel_hi:[1,0,0]" : "+v"(aH.x) : "v"(q.z));
    asm("v_fma_mix_f32 %0, %1, 1.0, %0 op_sel:[1,0,0] op_sel_hi:[1,0,0]" : "+v"(aH.y) : "v"(q.z));
    asm("v_fma_mix_f32 %0, %1, 1.0, %0 op_sel:[0,0,0] op_sel_hi:[1,0,0]" : "+v"(aH.z) : "v"(q.w));
    asm("v_fma_mix_f32 %0, %1, 1.0, %0 op_sel:[1,0,0] op_sel_hi:[1,0,0]" : "+v"(aH.w) : "v"(q.w));
}

__device__ __forceinline__ void acc_row4s(float4& aL, float4& aH, uint4 q, float s) {
    asm("v_fma_mix_f32 %0, %1, %2, %0 op_sel:[0,0,0] op_sel_hi:[1,0,0]" : "+v"(aL.x) : "v"(q.x), "v"(s));
    asm("v_fma_mix_f32 %0, %1, %2, %0 op_sel:[1,0,0] op_sel_hi:[1,0,0]" : "+v"(aL.y) : "v"(q.x), "v"(s));
    asm("v_fma_mix_f32 %0, %1, %2, %0 op_sel:[0,0,0] op_sel_hi:[1,0,0]" : "+v"(aL.z) : "v"(q.y), "v"(s));
    asm("v_fma_mix_f32 %0, %1, %2, %0 op_sel:[1,0,0] op_sel_hi:[1,0,0]" : "+v"(aL.w) : "v"(q.y), "v"(s));
    asm("v_fma_mix_f32 %0, %1, %2, %0 op_sel:[0,0,0] op_sel_hi:[1,0,0]" : "+v"(aH.x) : "v"(q.z), "v"(s));
    asm("v_fma_mix_f32 %0, %1, %2, %0 op_sel:[1,0,0] op_sel_hi:[1,0,0]" : "+v"(aH.y) : "v"(q.z), "v"(s));
    asm("v_fma_mix_f32 %0, %1, %2, %0 op_sel:[0,0,0] op_sel_hi:[1,0,0]" : "+v"(aH.z) : "v"(q.w), "v"(s));
    asm("v_fma_mix_f32 %0, %1, %2, %0 op_sel:[1,0,0] op_sel_hi:[1,0,0]" : "+v"(aH.w) : "v"(q.w), "v"(s));
}

// ---------------- CSR aggregation + bias + ReLU + BN (+ optional classifier) ----------------
// 16 lanes/node, uint4 gathers. SRC_SCALE: rows are UNscaled h; multiply by dinv[src] in the
// fma_mix (layer 1 only — GEMM1 is fused pre-dinv). Otherwise rows arrive pre-scaled.

template <bool FUSE_CLS, bool SRC_SCALE>
__global__ __launch_bounds__(256) void k_aggregate(const uint4* __restrict__ Ah,
                                                   const int2* __restrict__ offs2,
                                                   const int* __restrict__ er,
                                                   const float* __restrict__ dinv,
                                                   const float* __restrict__ bias,
                                                   const float* __restrict__ g,
                                                   const float* __restrict__ be,
                                                   const float* __restrict__ rm,
                                                   const float* __restrict__ rv,
                                                   uint4* __restrict__ Hout,
                                                   const float* __restrict__ Wc,
                                                   const float* __restrict__ bc,
                                                   float* __restrict__ out, int n) {
    int lane = threadIdx.x & 15;
    int node = blockIdx.x * 16 + (threadIdx.x >> 4);
    if (node >= n) return;

    const char* AhB = (const char*)Ah;
    unsigned int l16 = (unsigned int)lane * 16u;

    float di = dinv[node];
    float4 aL = f4zero(), aH = f4zero();
    // self loop (weight folds to dinv^2)
    {
        uint4 qs = *(const uint4*)(AhB + (((unsigned int)node << 8) + l16));
        if (SRC_SCALE) acc_row4s(aL, aH, qs, di);
        else           acc_row4(aL, aH, qs);
    }

    int2 offc = offs2[node];
    int e0 = offc.x, e1 = offc.y;
    for (int e = e0; e < e1; e += 8) {
        int4 ra = *(const int4*)(er + e);
        int4 rb = *(const int4*)(er + e + 4);
        uint4 v0 = *(const uint4*)(AhB + ((unsigned int)ra.x + l16));
        uint4 v1 = *(const uint4*)(AhB + ((unsigned int)ra.y + l16));
        uint4 v2 = *(const uint4*)(AhB + ((unsigned int)ra.z + l16));
        uint4 v3 = *(const uint4*)(AhB + ((unsigned int)ra.w + l16));
        uint4 v4 = *(const uint4*)(AhB + ((unsigned int)rb.x + l16));
        uint4 v5 = *(const uint4*)(AhB + ((unsigned int)rb.y + l16));
        uint4 v6 = *(const uint4*)(AhB + ((unsigned int)rb.z + l16));
        uint4 v7 = *(const uint4*)(AhB + ((unsigned int)rb.w + l16));
        if (SRC_SCALE) {
            float d0 = dinv[(unsigned int)ra.x >> 8];
            float d1 = dinv[(unsigned int)ra.y >> 8];
            float d2 = dinv[(unsigned int)ra.z >> 8];
            float d3 = dinv[(unsigned int)ra.w >> 8];
            float d4 = dinv[(unsigned int)rb.x >> 8];
            float d5 = dinv[(unsigned int)rb.y >> 8];
            float d6 = dinv[(unsigned int)rb.z >> 8];
            float d7 = dinv[(unsigned int)rb.w >> 8];
            acc_row4s(aL, aH, v0, d0); acc_row4s(aL, aH, v1, d1);
            acc_row4s(aL, aH, v2, d2); acc_row4s(aL, aH, v3, d3);
            acc_row4s(aL, aH, v4, d4); acc_row4s(aL, aH, v5, d5);
            acc_row4s(aL, aH, v6, d6); acc_row4s(aL, aH, v7, d7);
        } else {
            acc_row4(aL, aH, v0); acc_row4(aL, aH, v1); acc_row4(aL, aH, v2); acc_row4(aL, aH, v3);
            acc_row4(aL, aH, v4); acc_row4(aL, aH, v5); acc_row4(aL, aH, v6); acc_row4(aL, aH, v7);
        }
    }

    aL.x *= di; aL.y *= di; aL.z *= di; aL.w *= di;
    aH.x *= di; aH.y *= di; aH.z *= di; aH.w *= di;

    // lane covers features [8*lane, 8*lane+8) -> float4 indices 2*lane, 2*lane+1
    float4 bL  = ((const float4*)bias)[2 * lane], bH  = ((const float4*)bias)[2 * lane + 1];
    float4 gL  = ((const float4*)g)[2 * lane],    gH  = ((const float4*)g)[2 * lane + 1];
    float4 beL = ((const float4*)be)[2 * lane],   beH = ((const float4*)be)[2 * lane + 1];
    float4 rmL = ((const float4*)rm)[2 * lane],   rmH = ((const float4*)rm)[2 * lane + 1];
    float4 rvL = ((const float4*)rv)[2 * lane],   rvH = ((const float4*)rv)[2 * lane + 1];

    float4 oL, oH;
    float v;
    v = fmaxf(aL.x + bL.x, 0.f); oL.x = (v - rmL.x) * rsqrtf(rvL.x + BN_EPS) * gL.x + beL.x;
    v = fmaxf(aL.y + bL.y, 0.f); oL.y = (v - rmL.y) * rsqrtf(rvL.y + BN_EPS) * gL.y + beL.y;
    v = fmaxf(aL.z + bL.z, 0.f); oL.z = (v - rmL.z) * rsqrtf(rvL.z + BN_EPS) * gL.z + beL.z;
    v = fmaxf(aL.w + bL.w, 0.f); oL.w = (v - rmL.w) * rsqrtf(rvL.w + BN_EPS) * gL.w + beL.w;
    v = fmaxf(aH.x + bH.x, 0.f); oH.x = (v - rmH.x) * rsqrtf(rvH.x + BN_EPS) * gH.x + beH.x;
    v = fmaxf(aH.y + bH.y, 0.f); oH.y = (v - rmH.y) * rsqrtf(rvH.y + BN_EPS) * gH.y + beH.y;
    v = fmaxf(aH.z + bH.z, 0.f); oH.z = (v - rmH.z) * rsqrtf(rvH.z + BN_EPS) * gH.z + beH.z;
    v = fmaxf(aH.w + bH.w, 0.f); oH.w = (v - rmH.w) * rsqrtf(rvH.w + BN_EPS) * gH.w + beH.w;

    if (!FUSE_CLS) {
        __half2 p0 = __floats2half2_rn(oL.x, oL.y);
        __half2 p1 = __floats2half2_rn(oL.z, oL.w);
        __half2 p2 = __floats2half2_rn(oH.x, oH.y);
        __half2 p3 = __floats2half2_rn(oH.z, oH.w);
        uint4 u;
        u.x = *(unsigned int*)&p0;
        u.y = *(unsigned int*)&p1;
        u.z = *(unsigned int*)&p2;
        u.w = *(unsigned int*)&p3;
        Hout[(size_t)node * 16 + lane] = u;
    } else {
        const float4* Wv = (const float4*)Wc;   // Wc[f][2]: float4 i = features 2i,2i+1
        float4 w0 = Wv[4 * lane];
        float4 w1 = Wv[4 * lane + 1];
        float4 w2 = Wv[4 * lane + 2];
        float4 w3 = Wv[4 * lane + 3];
        float p0 = oL.x * w0.x + oL.y * w0.z + oL.z * w1.x + oL.w * w1.z
                 + oH.x * w2.x + oH.y * w2.z + oH.z * w3.x + oH.w * w3.z;
        float p1 = oL.x * w0.y + oL.y * w0.w + oL.z * w1.y + oL.w * w1.w
                 + oH.x * w2.y + oH.y * w2.w + oH.z * w3.y + oH.w * w3.w;
#pragma unroll
        for (int d = 8; d >= 1; d >>= 1) {
            p0 += __shfl_down(p0, d, 16);
            p1 += __shfl_down(p1, d, 16);
        }
        if (lane == 0) {
            out[node * 2 + 0] = p0 + bc[0];
            out[node * 2 + 1] = p1 + bc[1];
        }
    }
}

// ---------------- launch ----------------

extern "C" void kernel_launch(void* const* d_in, const int* in_sizes, int n_in,
                              void* d_out, int out_size, void* d_ws, size_t ws_size,
                              hipStream_t stream) {
    const float* x   = (const float*)d_in[0];
    const int*   ei  = (const int*)d_in[1];
    const float* W1  = (const float*)d_in[2];
    const float* b1  = (const float*)d_in[3];
    const float* W2  = (const float*)d_in[4];
    const float* b2  = (const float*)d_in[5];
    const float* W3  = (const float*)d_in[6];
    const float* b3  = (const float*)d_in[7];
    const float* g1  = (const float*)d_in[8];
    const float* be1 = (const float*)d_in[9];
    const float* rm1 = (const float*)d_in[10];
    const float* rv1 = (const float*)d_in[11];
    const float* g2  = (const float*)d_in[12];
    const float* be2 = (const float*)d_in[13];
    const float* rm2 = (const float*)d_in[14];
    const float* rv2 = (const float*)d_in[15];
    const float* g3  = (const float*)d_in[16];
    const float* be3 = (const float*)d_in[17];
    const float* rm3 = (const float*)d_in[18];
    const float* rv3 = (const float*)d_in[19];
    const float* Wc  = (const float*)d_in[20];
    const float* bc  = (const float*)d_in[21];
    float* out = (float*)d_out;

    int n = in_sizes[0] / 128;
    int e = in_sizes[1] / 2;
    const int* src = ei;
    const int* dst = ei + e;

    char* ws = (char*)d_ws;
    size_t off = 0;
    auto alloc = [&](size_t bytes) -> char* {
        char* p = ws + off;
        off += (bytes + 255) & ~(size_t)255;
        return p;
    };
    int nA    = (e + CHUNK - 1) / CHUNK;
    int nbuck = (n + (1 << BBITS) - 1) >> BBITS;
    int tlen  = nbuck * nA;
    int erCap = e + (nbuck << 10) + 64;

    char*      bufA     = (char*) alloc((size_t)(n + 1) * 256);   // GEMM out f16 [n+1][128]
    char*      bufH     = (char*) alloc((size_t)n * 256);         // H f16; bed aliases this
    float*     dinv     = (float*)alloc((size_t)(n + 1) * 4);
    int2*      offs2    = (int2*) alloc((size_t)n * 8);
    int*       tableT   = (int*)  alloc((size_t)(tlen + 1) * 4);
    int*       parts    = (int*)  alloc(8192);
    int*       er       = (int*)  alloc((size_t)erCap * 4);
    _Float16*  pW       = (_Float16*)alloc(3 * 16384 * 2);
    (void)ws_size; (void)n_in; (void)out_size;

    // bed aliases bufH (dead until first aggregate; consumed by k_rank_finalize)
    int2* bed = (int2*)bufH;                         // e*8 = 12.8 MB < 25.6 MB

    int nbT   = (tlen + 1023) / 1024;
    int gT    = (tlen + 255) / 256;
    int gGemm = (n + 63) / 64;
    int gAgg  = (n + 15) / 16;

    k_pack_hist<<<24 + nA, 256, 0, stream>>>(W1, W2, W3, pW, dst, tableT, nA, nbuck, e);
    k_scan_block<<<nbT, 1024, 0, stream>>>(tableT, tableT, parts, tlen);
    k_scan_addp<<<gT, 256, 0, stream>>>(tableT, parts, tlen);
    // scatter (nA blocks) + layer-1 GEMM (dinv-free) in one launch
    k_scatter_gemm<<<nA + gGemm, 256, 0, stream>>>(src, dst, tableT, bed, nA, nbuck, e,
                                                   x, pW, (uint4*)bufA, n);
    k_rank_finalize<<<nbuck, 256, 0, stream>>>(bed, tableT, offs2, er, dinv,
                                               (unsigned int*)(bufA + (size_t)n * 256),
                                               nA, nbuck, n, e);

    // layer 1 aggregate (bufA unscaled -> bufH), dinv[src] applied in fma_mix
    k_aggregate<false, true><<<gAgg, 256, 0, stream>>>((const uint4*)bufA, offs2, er, dinv,
                                                       b1, g1, be1, rm1, rv1, (uint4*)bufH,
                                                       nullptr, nullptr, nullptr, n);
    // layer 2 GEMM (bufH -> bufA, pre-scaled via aggregate output? no: unscaled h), agg2
    k_gemm_mfma<<<gGemm, 256, 0, stream>>>(bufH, pW + 16384, (uint4*)bufA, n);
    k_aggregate<false, true><<<gAgg, 256, 0, stream>>>((const uint4*)bufA, offs2, er, dinv,
                                                       b2, g2, be2, rm2, rv2, (uint4*)bufH,
                                                       nullptr, nullptr, nullptr, n);
    // layer 3 GEMM (bufH -> bufA), aggregate + classifier (bufA -> out)
    k_gemm_mfma<<<gGemm, 256, 0, stream>>>(bufH, pW + 32768, (uint4*)bufA, n);
    k_aggregate<true, true><<<gAgg, 256, 0, stream>>>((const uint4*)bufA, offs2, er, dinv,
                                                      b3, g3, be3, rm3, rv3, nullptr,
                                                      Wc, bc, out, n);
}

// Round 8
// 379.887 us; speedup vs baseline: 1.1519x; 1.0275x over previous
//
#include <hip/hip_runtime.h>
#include <hip/hip_fp16.h>

#define BN_EPS 1e-5f
#define CHUNK 4096            // edges per bucketing block (hist and scatter must match)
#define BBITS 7               // 128 nodes per bucket

typedef _Float16 half8 __attribute__((ext_vector_type(8)));
typedef float f32x4 __attribute__((ext_vector_type(4)));
typedef unsigned int u32x4 __attribute__((ext_vector_type(4)));

__device__ __forceinline__ float4 f4zero() { return make_float4(0.f, 0.f, 0.f, 0.f); }

// ---------------- K1: packW(all 3) + bucket histogram (LDS atomics only) ----------------

__global__ __launch_bounds__(256) void k_pack_hist(const float* __restrict__ W1,
                                                   const float* __restrict__ W2,
                                                   const float* __restrict__ W3,
                                                   _Float16* __restrict__ pW,
                                                   const int* __restrict__ dst,
                                                   int* __restrict__ tableT,
                                                   int nA, int nbuck, int e) {
    __shared__ int h[1024];
    int tid = threadIdx.x;
    if (blockIdx.x < 24) {            // W pre-pack: f32 [128][128] -> f16 B-fragment order
        int t = blockIdx.x * 256 + tid;   // 0..6143
        int wi = t >> 11;
        int tt = t & 2047;
        const float* W = (wi == 0) ? W1 : ((wi == 1) ? W2 : W3);
        int kc = tt >> 9;
        int rem = tt & 511;
        int ct = rem >> 6;
        int lane = rem & 63;
        int q = lane >> 4;
        int col = ct * 16 + (lane & 15);
        half8 hh;
#pragma unroll
        for (int j = 0; j < 8; ++j)
            hh[j] = (_Float16)W[(kc * 32 + q * 8 + j) * 128 + col];
        *(half8*)(pW + (size_t)t * 8) = hh;
        return;
    }
    int blk = blockIdx.x - 24;
    for (int k = tid; k < 1024; k += 256) h[k] = 0;
    __syncthreads();
    int base = blk * CHUNK;
    if (base + CHUNK <= e) {
        const int4* d4 = (const int4*)(dst + base);
#pragma unroll
        for (int t = 0; t < CHUNK / 1024; ++t) {
            int4 d = d4[t * 256 + tid];
            atomicAdd(&h[d.x >> BBITS], 1);
            atomicAdd(&h[d.y >> BBITS], 1);
            atomicAdd(&h[d.z >> BBITS], 1);
            atomicAdd(&h[d.w >> BBITS], 1);
        }
    } else {
        for (int i = base + tid; i < e; i += 256)
            atomicAdd(&h[dst[i] >> BBITS], 1);
    }
    __syncthreads();
    for (int k = tid; k < nbuck; k += 256)
        tableT[(size_t)k * nA + blk] = h[k];
}

// ---------------- K2/K3: 2-op exclusive scan of tableT ----------------

__global__ __launch_bounds__(1024) void k_scan_block(const int* __restrict__ in,
                                                     int* __restrict__ outp,
                                                     int* __restrict__ partials, int len) {
    __shared__ int s[1024];
    int t = threadIdx.x;
    int gid = blockIdx.x * 1024 + t;
    int v = (gid < len) ? in[gid] : 0;
    int x = v;
    s[t] = x;
    __syncthreads();
    for (int d = 1; d < 1024; d <<= 1) {
        int y = (t >= d) ? s[t - d] : 0;
        __syncthreads();
        x += y;
        s[t] = x;
        __syncthreads();
    }
    if (gid < len) outp[gid] = x - v;
    if (t == 1023) partials[blockIdx.x] = x;
}

__global__ __launch_bounds__(256) void k_scan_addp(int* __restrict__ data,
                                                   const int* __restrict__ partials, int len) {
    __shared__ int red[256];
    int tid = threadIdx.x;
    int K = blockIdx.x >> 2;          // number of preceding 1024-segments
    int s = 0;
    for (int t = tid; t < K; t += 256) s += partials[t];
    red[tid] = s;
    __syncthreads();
    for (int d = 128; d > 0; d >>= 1) {
        if (tid < d) red[tid] += red[tid + d];
        __syncthreads();
    }
    int gid = blockIdx.x * 256 + tid;
    if (gid < len) data[gid] += red[0];
}

// ---------------- K4: bucket-grouped COO scatter, 1024 threads (16 waves/block) ----------

__global__ __launch_bounds__(1024) void k_scatter(const int* __restrict__ src,
                                                  const int* __restrict__ dst,
                                                  const int* __restrict__ tableT,
                                                  int2* __restrict__ bed,
                                                  int nA, int nbuck, int e) {
    __shared__ int cur[1024];
    int blk = blockIdx.x, tid = threadIdx.x;
    for (int k = tid; k < nbuck; k += 1024)
        cur[k] = tableT[(size_t)k * nA + blk];
    __syncthreads();
    int base = blk * CHUNK;
    if (base + CHUNK <= e) {
        int4 s = ((const int4*)(src + base))[tid];
        int4 d = ((const int4*)(dst + base))[tid];
        int p0 = atomicAdd(&cur[d.x >> BBITS], 1); bed[p0] = make_int2(s.x, d.x);
        int p1 = atomicAdd(&cur[d.y >> BBITS], 1); bed[p1] = make_int2(s.y, d.y);
        int p2 = atomicAdd(&cur[d.z >> BBITS], 1); bed[p2] = make_int2(s.z, d.z);
        int p3 = atomicAdd(&cur[d.w >> BBITS], 1); bed[p3] = make_int2(s.w, d.w);
    } else {
        for (int i = base + tid; i < e; i += 1024) {
            int d = dst[i];
            int p = atomicAdd(&cur[d >> BBITS], 1);
            bed[p] = make_int2(src[i], d);
        }
    }
}

// ---------------- GEMM body (LDS-W staged, f32 A, NO dinv): used for layer-1 ----------------

template <bool AF32>
__device__ __forceinline__ void gemm_body(int bid, int tid, char* smem,
                                          const void* __restrict__ Av,
                                          const _Float16* __restrict__ pW,
                                          uint4* __restrict__ C, int n) {
    uint4* sW = (uint4*)smem;
    {
        const uint4* gW = (const uint4*)pW;
#pragma unroll
        for (int i = 0; i < 8; ++i) sW[tid + 256 * i] = gW[tid + 256 * i];
    }
    __syncthreads();

    int wave = tid >> 6, lane = tid & 63;
    int quad = lane >> 4, l16 = lane & 15;
    int row0 = bid * 64 + wave * 16;
    int arow = row0 + l16;
    int arowc = (arow < n) ? arow : (n - 1);

    half8 af[4];
    if (AF32) {
        const float* A = (const float*)Av + (size_t)arowc * 128 + quad * 8;
#pragma unroll
        for (int kc = 0; kc < 4; ++kc) {
            float4 lo = *(const float4*)(A + kc * 32);
            float4 hi = *(const float4*)(A + kc * 32 + 4);
            half8 h;
            h[0] = (_Float16)lo.x; h[1] = (_Float16)lo.y;
            h[2] = (_Float16)lo.z; h[3] = (_Float16)lo.w;
            h[4] = (_Float16)hi.x; h[5] = (_Float16)hi.y;
            h[6] = (_Float16)hi.z; h[7] = (_Float16)hi.w;
            af[kc] = h;
        }
    } else {
        const _Float16* A = (const _Float16*)Av + (size_t)arowc * 128 + quad * 8;
#pragma unroll
        for (int kc = 0; kc < 4; ++kc)
            af[kc] = *(const half8*)(A + kc * 32);
    }

    f32x4 acc[8];
#pragma unroll
    for (int ct = 0; ct < 8; ++ct) acc[ct] = (f32x4){0.f, 0.f, 0.f, 0.f};

#pragma unroll
    for (int kc = 0; kc < 4; ++kc) {
#pragma unroll
        for (int ct = 0; ct < 8; ++ct) {
            half8 bf = *(half8*)&sW[(kc * 8 + ct) * 64 + lane];
            acc[ct] = __builtin_amdgcn_mfma_f32_16x16x32_f16(af[kc], bf, acc[ct], 0, 0, 0);
        }
    }

    __syncthreads();

    _Float16* eb = (_Float16*)smem + wave * 16 * 136;   // 136 halfs = 272 B row stride
#pragma unroll
    for (int ct = 0; ct < 8; ++ct)
#pragma unroll
        for (int r = 0; r < 4; ++r)
            eb[(quad * 4 + r) * 136 + ct * 16 + l16] = (_Float16)(acc[ct][r]);

#pragma unroll
    for (int i = 0; i < 4; ++i) {
        int linear = i * 64 + lane;
        int r = linear >> 4, c = linear & 15;
        uint4 v = *(uint4*)((char*)eb + r * 272 + c * 16);
        int row = row0 + r;
        if (row < n) C[(size_t)row * 16 + c] = v;
    }
}

// ---------------- K5: per-bucket rank/offsets/er/dinv (+ zero pads & counters) ∥ GEMM1 ----

__global__ __launch_bounds__(256) void k_rank_gemm1(const int2* __restrict__ bed,
                                                    const int* __restrict__ tableT,
                                                    int2* __restrict__ offs2,
                                                    int* __restrict__ er,
                                                    float* __restrict__ dinv,
                                                    unsigned int* __restrict__ pad0,
                                                    unsigned int* __restrict__ pad1,
                                                    unsigned int* __restrict__ pad2,
                                                    int* __restrict__ cntAll, int cntLen,
                                                    const float* __restrict__ x,
                                                    const _Float16* __restrict__ pW,
                                                    uint4* __restrict__ C,
                                                    int nA, int nbuck, int n, int e) {
    __shared__ char smem[32768];
    int tid = threadIdx.x;
    int b = blockIdx.x;
    if (b >= nbuck) {                       // layer-1 GEMM from f32 x (dinv-free)
        gemm_body<true>(b - nbuck, tid, smem, x, pW, C, n);
        return;
    }
    int* lcnt  = (int*)smem;
    int* lscan = lcnt + 128;
    int* loff  = lscan + 128;
    { int ci = b * 256 + tid; if (ci < cntLen) cntAll[ci] = 0; }   // zero tile flags
    if (b == 0) {
        if (tid < 64) { pad0[tid] = 0u; pad1[tid] = 0u; pad2[tid] = 0u; }  // pad rows
        if (tid == 0) dinv[n] = 0.f;        // dummy-row scale (layer-1 SRC_SCALE path)
    }
    if (tid < 128) lcnt[tid] = 0;
    __syncthreads();
    int start = tableT[(size_t)b * nA];
    int end = (b + 1 < nbuck) ? tableT[(size_t)(b + 1) * nA] : e;
    for (int i = start + tid; i < end; i += 256)
        atomicAdd(&lcnt[bed[i].y & 127], 1);
    __syncthreads();
    int padded = 0;
    if (tid < 128) {
        padded = (lcnt[tid] + 7) & ~7;
        lscan[tid] = padded;
    }
    __syncthreads();
    for (int d = 1; d < 128; d <<= 1) {          // Hillis-Steele inclusive scan over 128
        int y = (tid < 128 && tid >= d) ? lscan[tid - d] : 0;
        __syncthreads();
        if (tid < 128) lscan[tid] += y;
        __syncthreads();
    }
    int ebase = start + (b << 10);               // pad slack <= 128*7 < 1024 per bucket
    if (tid < 128) {
        loff[tid] = lscan[tid] - padded;
        int node = (b << BBITS) + tid;
        if (node < n) {
            int c = lcnt[tid];
            int o = ebase + loff[tid];
            offs2[node] = make_int2(o, o + padded);
            dinv[node] = rsqrtf((float)(c + 1));
            for (int j = c; j < padded; ++j) er[o + j] = n << 8;   // dummy zero-row
        }
    }
    __syncthreads();
    if (tid < 128) lcnt[tid] = 0;                // reuse as rank cursors
    __syncthreads();
    for (int i = start + tid; i < end; i += 256) {
        int2 q = bed[i];
        int l = q.y & 127;
        int r = atomicAdd(&lcnt[l], 1);
        er[ebase + loff[l] + r] = q.x << 8;      // BYTE offsets (src*256)
    }
}

// ---------------- fma_mix accumulate ----------------
// uint4 = 8 halfs: q.x -> f0,f1 | q.y -> f2,f3 | q.z -> f4,f5 | q.w -> f6,f7

__device__ __forceinline__ void acc_row4(float4& aL, float4& aH, uint4 q) {
    asm("v_fma_mix_f32 %0, %1, 1.0, %0 op_sel:[0,0,0] op_sel_hi:[1,0,0]" : "+v"(aL.x) : "v"(q.x));
    asm("v_fma_mix_f32 %0, %1, 1.0, %0 op_sel:[1,0,0] op_sel_hi:[1,0,0]" : "+v"(aL.y) : "v"(q.x));
    asm("v_fma_mix_f32 %0, %1, 1.0, %0 op_sel:[0,0,0] op_sel_hi:[1,0,0]" : "+v"(aL.z) : "v"(q.y));
    asm("v_fma_mix_f32 %0, %1, 1.0, %0 op_sel:[1,0,0] op_sel_hi:[1,0,0]" : "+v"(aL.w) : "v"(q.y));
    asm("v_fma_mix_f32 %0, %1, 1.0, %0 op_sel:[0,0,0] op_sel_hi:[1,0,0]" : "+v"(aH.x) : "v"(q.z));
    asm("v_fma_mix_f32 %0, %1, 1.0, %0 op_sel:[1,0,0] op_sel_hi:[1,0,0]" : "+v"(aH.y) : "v"(q.z));
    asm("v_fma_mix_f32 %0, %1, 1.0, %0 op_sel:[0,0,0] op_sel_hi:[1,0,0]" : "+v"(aH.z) : "v"(q.w));
    asm("v_fma_mix_f32 %0, %1, 1.0, %0 op_sel:[1,0,0] op_sel_hi:[1,0,0]" : "+v"(aH.w) : "v"(q.w));
}

__device__ __forceinline__ void acc_row4s(float4& aL, float4& aH, uint4 q, float s) {
    asm("v_fma_mix_f32 %0, %1, %2, %0 op_sel:[0,0,0] op_sel_hi:[1,0,0]" : "+v"(aL.x) : "v"(q.x), "v"(s));
    asm("v_fma_mix_f32 %0, %1, %2, %0 op_sel:[1,0,0] op_sel_hi:[1,0,0]" : "+v"(aL.y) : "v"(q.x), "v"(s));
    asm("v_fma_mix_f32 %0, %1, %2, %0 op_sel:[0,0,0] op_sel_hi:[1,0,0]" : "+v"(aL.z) : "v"(q.y), "v"(s));
    asm("v_fma_mix_f32 %0, %1, %2, %0 op_sel:[1,0,0] op_sel_hi:[1,0,0]" : "+v"(aL.w) : "v"(q.y), "v"(s));
    asm("v_fma_mix_f32 %0, %1, %2, %0 op_sel:[0,0,0] op_sel_hi:[1,0,0]" : "+v"(aH.x) : "v"(q.z), "v"(s));
    asm("v_fma_mix_f32 %0, %1, %2, %0 op_sel:[1,0,0] op_sel_hi:[1,0,0]" : "+v"(aH.y) : "v"(q.z), "v"(s));
    asm("v_fma_mix_f32 %0, %1, %2, %0 op_sel:[0,0,0] op_sel_hi:[1,0,0]" : "+v"(aH.z) : "v"(q.w), "v"(s));
    asm("v_fma_mix_f32 %0, %1, %2, %0 op_sel:[1,0,0] op_sel_hi:[1,0,0]" : "+v"(aH.w) : "v"(q.w), "v"(s));
}

// ---------------- fused: CSR aggregate (flagged sc1 stores) ∥ next-layer GEMM (spin) --------
// blocks [0,gAgg): 16-node aggregates; write Hout rows write-through (sc0 sc1 -> LLC, cross-XCD
// visible), vmcnt(0), bump per-64-row-tile counter. blocks [gAgg,..): each handles TWO 64-row
// GEMM tiles: spin on tile counter, then MFMA with W streamed from global, dinv epilogue.
// Deadlock-free: <=782 spinner blocks << resident-block capacity (>=1536).

template <bool SRC_SCALE>
__global__ __launch_bounds__(256) void k_agg_gemm(const uint4* __restrict__ Ah,
                                                  const int2* __restrict__ offs2,
                                                  const int* __restrict__ er,
                                                  const float* __restrict__ dinv,
                                                  const float* __restrict__ bias,
                                                  const float* __restrict__ g,
                                                  const float* __restrict__ be,
                                                  const float* __restrict__ rm,
                                                  const float* __restrict__ rv,
                                                  uint4* __restrict__ Hout,
                                                  int* __restrict__ cnt,
                                                  const _Float16* __restrict__ pW,
                                                  uint4* __restrict__ Cout,
                                                  int n, int gAgg) {
    __shared__ _Float16 ebs[4 * 16 * 136];    // 17408 B (gemm epilogue scratch)
    int tid = threadIdx.x;
    if ((int)blockIdx.x < gAgg) {
        // ---------------- aggregate path ----------------
        int lane = tid & 15;
        int node = blockIdx.x * 16 + (tid >> 4);
        if (node < n) {
            const char* AhB = (const char*)Ah;
            unsigned int l16b = (unsigned int)lane * 16u;
            float di = dinv[node];
            float4 aL = f4zero(), aH = f4zero();
            {
                uint4 qs = *(const uint4*)(AhB + (((unsigned int)node << 8) + l16b));
                if (SRC_SCALE) acc_row4s(aL, aH, qs, di);
                else           acc_row4(aL, aH, qs);
            }
            int2 offc = offs2[node];
            for (int ee = offc.x; ee < offc.y; ee += 8) {
                int4 ra = *(const int4*)(er + ee);
                int4 rb = *(const int4*)(er + ee + 4);
                uint4 v0 = *(const uint4*)(AhB + ((unsigned int)ra.x + l16b));
                uint4 v1 = *(const uint4*)(AhB + ((unsigned int)ra.y + l16b));
                uint4 v2 = *(const uint4*)(AhB + ((unsigned int)ra.z + l16b));
                uint4 v3 = *(const uint4*)(AhB + ((unsigned int)ra.w + l16b));
                uint4 v4 = *(const uint4*)(AhB + ((unsigned int)rb.x + l16b));
                uint4 v5 = *(const uint4*)(AhB + ((unsigned int)rb.y + l16b));
                uint4 v6 = *(const uint4*)(AhB + ((unsigned int)rb.z + l16b));
                uint4 v7 = *(const uint4*)(AhB + ((unsigned int)rb.w + l16b));
                if (SRC_SCALE) {
                    float d0 = dinv[(unsigned int)ra.x >> 8];
                    float d1 = dinv[(unsigned int)ra.y >> 8];
                    float d2 = dinv[(unsigned int)ra.z >> 8];
                    float d3 = dinv[(unsigned int)ra.w >> 8];
                    float d4 = dinv[(unsigned int)rb.x >> 8];
                    float d5 = dinv[(unsigned int)rb.y >> 8];
                    float d6 = dinv[(unsigned int)rb.z >> 8];
                    float d7 = dinv[(unsigned int)rb.w >> 8];
                    acc_row4s(aL, aH, v0, d0); acc_row4s(aL, aH, v1, d1);
                    acc_row4s(aL, aH, v2, d2); acc_row4s(aL, aH, v3, d3);
                    acc_row4s(aL, aH, v4, d4); acc_row4s(aL, aH, v5, d5);
                    acc_row4s(aL, aH, v6, d6); acc_row4s(aL, aH, v7, d7);
                } else {
                    acc_row4(aL, aH, v0); acc_row4(aL, aH, v1);
                    acc_row4(aL, aH, v2); acc_row4(aL, aH, v3);
                    acc_row4(aL, aH, v4); acc_row4(aL, aH, v5);
                    acc_row4(aL, aH, v6); acc_row4(aL, aH, v7);
                }
            }
            aL.x *= di; aL.y *= di; aL.z *= di; aL.w *= di;
            aH.x *= di; aH.y *= di; aH.z *= di; aH.w *= di;

            float4 bL  = ((const float4*)bias)[2 * lane], bH  = ((const float4*)bias)[2 * lane + 1];
            float4 gL  = ((const float4*)g)[2 * lane],    gH  = ((const float4*)g)[2 * lane + 1];
            float4 beL = ((const float4*)be)[2 * lane],   beH = ((const float4*)be)[2 * lane + 1];
            float4 rmL = ((const float4*)rm)[2 * lane],   rmH = ((const float4*)rm)[2 * lane + 1];
            float4 rvL = ((const float4*)rv)[2 * lane],   rvH = ((const float4*)rv)[2 * lane + 1];

            float4 oL, oH;
            float v;
            v = fmaxf(aL.x + bL.x, 0.f); oL.x = (v - rmL.x) * rsqrtf(rvL.x + BN_EPS) * gL.x + beL.x;
            v = fmaxf(aL.y + bL.y, 0.f); oL.y = (v - rmL.y) * rsqrtf(rvL.y + BN_EPS) * gL.y + beL.y;
            v = fmaxf(aL.z + bL.z, 0.f); oL.z = (v - rmL.z) * rsqrtf(rvL.z + BN_EPS) * gL.z + beL.z;
            v = fmaxf(aL.w + bL.w, 0.f); oL.w = (v - rmL.w) * rsqrtf(rvL.w + BN_EPS) * gL.w + beL.w;
            v = fmaxf(aH.x + bH.x, 0.f); oH.x = (v - rmH.x) * rsqrtf(rvH.x + BN_EPS) * gH.x + beH.x;
            v = fmaxf(aH.y + bH.y, 0.f); oH.y = (v - rmH.y) * rsqrtf(rvH.y + BN_EPS) * gH.y + beH.y;
            v = fmaxf(aH.z + bH.z, 0.f); oH.z = (v - rmH.z) * rsqrtf(rvH.z + BN_EPS) * gH.z + beH.z;
            v = fmaxf(aH.w + bH.w, 0.f); oH.w = (v - rmH.w) * rsqrtf(rvH.w + BN_EPS) * gH.w + beH.w;

            __half2 p0 = __floats2half2_rn(oL.x, oL.y);
            __half2 p1 = __floats2half2_rn(oL.z, oL.w);
            __half2 p2 = __floats2half2_rn(oH.x, oH.y);
            __half2 p3 = __floats2half2_rn(oH.z, oH.w);
            u32x4 u;
            u.x = *(unsigned int*)&p0;
            u.y = *(unsigned int*)&p1;
            u.z = *(unsigned int*)&p2;
            u.w = *(unsigned int*)&p3;
            const uint4* pp = Hout + (size_t)node * 16 + lane;
            asm volatile("global_store_dwordx4 %0, %1, off sc0 sc1"
                         :: "v"(pp), "v"(u) : "memory");
        }
        asm volatile("s_waitcnt vmcnt(0)" ::: "memory");
        __syncthreads();
        if (tid == 0) atomicAdd(&cnt[blockIdx.x >> 2], 1);
        return;
    }
    // ---------------- gemm path: two 64-row tiles per block ----------------
    int bid2 = (int)blockIdx.x - gAgg;
    int wave = tid >> 6, lane = tid & 63;
    int quad = lane >> 4, l16 = lane & 15;
#pragma unroll 1
    for (int half = 0; half < 2; ++half) {
        int bid = bid2 * 2 + half;
        if (bid * 64 >= n) break;
        int rem = n - bid * 64;
        int expct = (rem >= 64) ? 4 : ((rem + 15) >> 4);
        if (tid == 0) {
            while (atomicAdd(&cnt[bid], 0) < expct) __builtin_amdgcn_s_sleep(8);
        }
        __syncthreads();                     // flag acquired; also WAR fence for ebs reuse

        int row0 = bid * 64 + wave * 16;
        int arow = row0 + l16;
        int arowc = (arow < n) ? arow : (n - 1);
        const _Float16* A = (const _Float16*)Hout + (size_t)arowc * 128 + quad * 8;
        half8 af[4];
#pragma unroll
        for (int kc = 0; kc < 4; ++kc)
            af[kc] = *(const half8*)(A + kc * 32);

        f32x4 acc[8];
#pragma unroll
        for (int ct = 0; ct < 8; ++ct) acc[ct] = (f32x4){0.f, 0.f, 0.f, 0.f};
#pragma unroll
        for (int kc = 0; kc < 4; ++kc) {
#pragma unroll
            for (int ct = 0; ct < 8; ++ct) {
                half8 bf = *(const half8*)(pW + (size_t)((kc * 8 + ct) * 64 + lane) * 8);
                acc[ct] = __builtin_amdgcn_mfma_f32_16x16x32_f16(af[kc], bf, acc[ct], 0, 0, 0);
            }
        }

        _Float16* eb = ebs + wave * 16 * 136;
        float dv[4];
#pragma unroll
        for (int r = 0; r < 4; ++r) {
            int rr = row0 + quad * 4 + r;
            dv[r] = dinv[(rr < n) ? rr : (n - 1)];
        }
#pragma unroll
        for (int ct = 0; ct < 8; ++ct)
#pragma unroll
            for (int r = 0; r < 4; ++r)
                eb[(quad * 4 + r) * 136 + ct * 16 + l16] = (_Float16)(acc[ct][r] * dv[r]);
        __syncthreads();
#pragma unroll
        for (int i = 0; i < 4; ++i) {
            int linear = i * 64 + lane;
            int r = linear >> 4, c = linear & 15;
            uint4 v = *(uint4*)((char*)eb + r * 272 + c * 16);
            int row = row0 + r;
            if (row < n) Cout[(size_t)row * 16 + c] = v;
        }
    }
}

// ---------------- final layer: aggregate (pre-scaled source) + bias/ReLU/BN + classifier ----

__global__ __launch_bounds__(256) void k_agg_cls(const uint4* __restrict__ Ah,
                                                 const int2* __restrict__ offs2,
                                                 const int* __restrict__ er,
                                                 const float* __restrict__ dinv,
                                                 const float* __restrict__ bias,
                                                 const float* __restrict__ g,
                                                 const float* __restrict__ be,
                                                 const float* __restrict__ rm,
                                                 const float* __restrict__ rv,
                                                 const float* __restrict__ Wc,
                                                 const float* __restrict__ bc,
                                                 float* __restrict__ out, int n) {
    int lane = threadIdx.x & 15;
    int node = blockIdx.x * 16 + (threadIdx.x >> 4);
    if (node >= n) return;

    const char* AhB = (const char*)Ah;
    unsigned int l16b = (unsigned int)lane * 16u;

    float4 aL = f4zero(), aH = f4zero();
    acc_row4(aL, aH, *(const uint4*)(AhB + (((unsigned int)node << 8) + l16b)));

    int2 offc = offs2[node];
    for (int ee = offc.x; ee < offc.y; ee += 8) {
        int4 ra = *(const int4*)(er + ee);
        int4 rb = *(const int4*)(er + ee + 4);
        uint4 v0 = *(const uint4*)(AhB + ((unsigned int)ra.x + l16b));
        uint4 v1 = *(const uint4*)(AhB + ((unsigned int)ra.y + l16b));
        uint4 v2 = *(const uint4*)(AhB + ((unsigned int)ra.z + l16b));
        uint4 v3 = *(const uint4*)(AhB + ((unsigned int)ra.w + l16b));
        uint4 v4 = *(const uint4*)(AhB + ((unsigned int)rb.x + l16b));
        uint4 v5 = *(const uint4*)(AhB + ((unsigned int)rb.y + l16b));
        uint4 v6 = *(const uint4*)(AhB + ((unsigned int)rb.z + l16b));
        uint4 v7 = *(const uint4*)(AhB + ((unsigned int)rb.w + l16b));
        acc_row4(aL, aH, v0); acc_row4(aL, aH, v1); acc_row4(aL, aH, v2); acc_row4(aL, aH, v3);
        acc_row4(aL, aH, v4); acc_row4(aL, aH, v5); acc_row4(aL, aH, v6); acc_row4(aL, aH, v7);
    }

    float di = dinv[node];
    aL.x *= di; aL.y *= di; aL.z *= di; aL.w *= di;
    aH.x *= di; aH.y *= di; aH.z *= di; aH.w *= di;

    float4 bL  = ((const float4*)bias)[2 * lane], bH  = ((const float4*)bias)[2 * lane + 1];
    float4 gL  = ((const float4*)g)[2 * lane],    gH  = ((const float4*)g)[2 * lane + 1];
    float4 beL = ((const float4*)be)[2 * lane],   beH = ((const float4*)be)[2 * lane + 1];
    float4 rmL = ((const float4*)rm)[2 * lane],   rmH = ((const float4*)rm)[2 * lane + 1];
    float4 rvL = ((const float4*)rv)[2 * lane],   rvH = ((const float4*)rv)[2 * lane + 1];

    float4 oL, oH;
    float v;
    v = fmaxf(aL.x + bL.x, 0.f); oL.x = (v - rmL.x) * rsqrtf(rvL.x + BN_EPS) * gL.x + beL.x;
    v = fmaxf(aL.y + bL.y, 0.f); oL.y = (v - rmL.y) * rsqrtf(rvL.y + BN_EPS) * gL.y + beL.y;
    v = fmaxf(aL.z + bL.z, 0.f); oL.z = (v - rmL.z) * rsqrtf(rvL.z + BN_EPS) * gL.z + beL.z;
    v = fmaxf(aL.w + bL.w, 0.f); oL.w = (v - rmL.w) * rsqrtf(rvL.w + BN_EPS) * gL.w + beL.w;
    v = fmaxf(aH.x + bH.x, 0.f); oH.x = (v - rmH.x) * rsqrtf(rvH.x + BN_EPS) * gH.x + beH.x;
    v = fmaxf(aH.y + bH.y, 0.f); oH.y = (v - rmH.y) * rsqrtf(rvH.y + BN_EPS) * gH.y + beH.y;
    v = fmaxf(aH.z + bH.z, 0.f); oH.z = (v - rmH.z) * rsqrtf(rvH.z + BN_EPS) * gH.z + beH.z;
    v = fmaxf(aH.w + bH.w, 0.f); oH.w = (v - rmH.w) * rsqrtf(rvH.w + BN_EPS) * gH.w + beH.w;

    const float4* Wv = (const float4*)Wc;   // Wc[f][2]: float4 i = features 2i,2i+1
    float4 w0 = Wv[4 * lane];
    float4 w1 = Wv[4 * lane + 1];
    float4 w2 = Wv[4 * lane + 2];
    float4 w3 = Wv[4 * lane + 3];
    float p0 = oL.x * w0.x + oL.y * w0.z + oL.z * w1.x + oL.w * w1.z
             + oH.x * w2.x + oH.y * w2.z + oH.z * w3.x + oH.w * w3.z;
    float p1 = oL.x * w0.y + oL.y * w0.w + oL.z * w1.y + oL.w * w1.w
             + oH.x * w2.y + oH.y * w2.w + oH.z * w3.y + oH.w * w3.w;
#pragma unroll
    for (int d = 8; d >= 1; d >>= 1) {
        p0 += __shfl_down(p0, d, 16);
        p1 += __shfl_down(p1, d, 16);
    }
    if (lane == 0) {
        out[node * 2 + 0] = p0 + bc[0];
        out[node * 2 + 1] = p1 + bc[1];
    }
}

// ---------------- launch ----------------

extern "C" void kernel_launch(void* const* d_in, const int* in_sizes, int n_in,
                              void* d_out, int out_size, void* d_ws, size_t ws_size,
                              hipStream_t stream) {
    const float* x   = (const float*)d_in[0];
    const int*   ei  = (const int*)d_in[1];
    const float* W1  = (const float*)d_in[2];
    const float* b1  = (const float*)d_in[3];
    const float* W2  = (const float*)d_in[4];
    const float* b2  = (const float*)d_in[5];
    const float* W3  = (const float*)d_in[6];
    const float* b3  = (const float*)d_in[7];
    const float* g1  = (const float*)d_in[8];
    const float* be1 = (const float*)d_in[9];
    const float* rm1 = (const float*)d_in[10];
    const float* rv1 = (const float*)d_in[11];
    const float* g2  = (const float*)d_in[12];
    const float* be2 = (const float*)d_in[13];
    const float* rm2 = (const float*)d_in[14];
    const float* rv2 = (const float*)d_in[15];
    const float* g3  = (const float*)d_in[16];
    const float* be3 = (const float*)d_in[17];
    const float* rm3 = (const float*)d_in[18];
    const float* rv3 = (const float*)d_in[19];
    const float* Wc  = (const float*)d_in[20];
    const float* bc  = (const float*)d_in[21];
    float* out = (float*)d_out;

    int n = in_sizes[0] / 128;
    int e = in_sizes[1] / 2;
    const int* src = ei;
    const int* dst = ei + e;

    char* ws = (char*)d_ws;
    size_t off = 0;
    auto alloc = [&](size_t bytes) -> char* {
        char* p = ws + off;
        off += (bytes + 255) & ~(size_t)255;
        return p;
    };
    int nA    = (e + CHUNK - 1) / CHUNK;
    int nbuck = (n + (1 << BBITS) - 1) >> BBITS;
    int tlen  = nbuck * nA;
    int erCap = e + (nbuck << 10) + 64;
    int gAgg  = (n + 15) / 16;
    int gGemm = (n + 63) / 64;      // 64-row flag tiles
    int gHalf = (n + 127) / 128;    // gemm blocks in fused launches (2 tiles each)

    char*      buf0     = (char*) alloc((size_t)(n + 1) * 256);   // gemm1 out (unscaled h1)
    char*      buf1     = (char*) alloc((size_t)(n + 1) * 256);   // H1 / gemm3 out
    char*      buf2     = (char*) alloc((size_t)(n + 1) * 256);   // gemm2 out; bed aliases
    float*     dinv     = (float*)alloc((size_t)(n + 1) * 4);
    int2*      offs2    = (int2*) alloc((size_t)n * 8);
    int*       tableT   = (int*)  alloc((size_t)(tlen + 1) * 4);
    int*       parts    = (int*)  alloc(8192);
    int*       er       = (int*)  alloc((size_t)erCap * 4);
    _Float16*  pW       = (_Float16*)alloc(3 * 16384 * 2);
    int*       cntAll   = (int*)  alloc((size_t)2 * gGemm * 4);
    (void)ws_size; (void)n_in; (void)out_size;

    int2* bed = (int2*)buf2;                      // e*8 = 12.8 MB < 25.6 MB

    int nbT = (tlen + 1023) / 1024;
    int gT  = (tlen + 255) / 256;

    k_pack_hist<<<24 + nA, 256, 0, stream>>>(W1, W2, W3, pW, dst, tableT, nA, nbuck, e);
    k_scan_block<<<nbT, 1024, 0, stream>>>(tableT, tableT, parts, tlen);
    k_scan_addp<<<gT, 256, 0, stream>>>(tableT, parts, tlen);
    k_scatter<<<nA, 1024, 0, stream>>>(src, dst, tableT, bed, nA, nbuck, e);
    // rank/finalize (782 blocks) ∥ layer-1 GEMM (1563 blocks) — independent data
    k_rank_gemm1<<<nbuck + gGemm, 256, 0, stream>>>(
        bed, tableT, offs2, er, dinv,
        (unsigned int*)(buf0 + (size_t)n * 256),
        (unsigned int*)(buf1 + (size_t)n * 256),
        (unsigned int*)(buf2 + (size_t)n * 256),
        cntAll, 2 * gGemm, x, pW, (uint4*)buf0, nA, nbuck, n, e);

    // layer1 agg (buf0 unscaled -> buf1, SRC_SCALE) ∥ layer2 GEMM (buf1 -> buf2, ×dinv)
    k_agg_gemm<true><<<gAgg + gHalf, 256, 0, stream>>>(
        (const uint4*)buf0, offs2, er, dinv, b1, g1, be1, rm1, rv1,
        (uint4*)buf1, cntAll, pW + 16384, (uint4*)buf2, n, gAgg);
    // layer2 agg (buf2 pre-scaled -> buf0) ∥ layer3 GEMM (buf0 -> buf1, ×dinv)
    k_agg_gemm<false><<<gAgg + gHalf, 256, 0, stream>>>(
        (const uint4*)buf2, offs2, er, dinv, b2, g2, be2, rm2, rv2,
        (uint4*)buf0, cntAll + gGemm, pW + 32768, (uint4*)buf1, n, gAgg);
    // layer3 agg (buf1 pre-scaled) + classifier
    k_agg_cls<<<gAgg, 256, 0, stream>>>((const uint4*)buf1, offs2, er, dinv,
                                        b3, g3, be3, rm3, rv3, Wc, bc, out, n);
}

// Round 9
// 374.015 us; speedup vs baseline: 1.1699x; 1.0157x over previous
//
#include <hip/hip_runtime.h>
#include <hip/hip_fp16.h>

#define BN_EPS 1e-5f
#define CHUNK 8192            // edges per bucketing block (hist and scatter must match)
#define BBITS 9               // 512 nodes per bucket

typedef _Float16 half8 __attribute__((ext_vector_type(8)));
typedef float f32x4 __attribute__((ext_vector_type(4)));

__device__ __forceinline__ float4 f4zero() { return make_float4(0.f, 0.f, 0.f, 0.f); }

// ---------------- K1: packW(all 3) + bucket histogram (LDS atomics, 1024 thr) ----------------

__global__ __launch_bounds__(1024) void k_pack_hist(const float* __restrict__ W1,
                                                    const float* __restrict__ W2,
                                                    const float* __restrict__ W3,
                                                    _Float16* __restrict__ pW,
                                                    const int* __restrict__ dst,
                                                    int* __restrict__ tableT,
                                                    int nA, int nbuck, int e) {
    __shared__ int h[256];
    int tid = threadIdx.x;
    if (blockIdx.x < 6) {             // W pre-pack: f32 [128][128] -> f16 B-fragment order
        int t = blockIdx.x * 1024 + tid;  // 0..6143
        int wi = t >> 11;
        int tt = t & 2047;
        const float* W = (wi == 0) ? W1 : ((wi == 1) ? W2 : W3);
        int kc = tt >> 9;
        int rem = tt & 511;
        int ct = rem >> 6;
        int lane = rem & 63;
        int q = lane >> 4;
        int col = ct * 16 + (lane & 15);
        half8 hh;
#pragma unroll
        for (int j = 0; j < 8; ++j)
            hh[j] = (_Float16)W[(kc * 32 + q * 8 + j) * 128 + col];
        *(half8*)(pW + (size_t)t * 8) = hh;
        return;
    }
    int blk = blockIdx.x - 6;
    if (tid < 256) h[tid] = 0;
    __syncthreads();
    int base = blk * CHUNK;
    if (base + CHUNK <= e) {
        const int4* d4 = (const int4*)(dst + base);
#pragma unroll
        for (int t = 0; t < CHUNK / 4096; ++t) {
            int4 d = d4[t * 1024 + tid];
            atomicAdd(&h[d.x >> BBITS], 1);
            atomicAdd(&h[d.y >> BBITS], 1);
            atomicAdd(&h[d.z >> BBITS], 1);
            atomicAdd(&h[d.w >> BBITS], 1);
        }
    } else {
        for (int i = base + tid; i < e; i += 1024)
            atomicAdd(&h[dst[i] >> BBITS], 1);
    }
    __syncthreads();
    for (int k = tid; k < nbuck; k += 1024)
        tableT[(size_t)k * nA + blk] = h[k];
}

// ---------------- K2/K3: 2-op exclusive scan of tableT ----------------

__global__ __launch_bounds__(1024) void k_scan_block(const int* __restrict__ in,
                                                     int* __restrict__ outp,
                                                     int* __restrict__ partials, int len) {
    __shared__ int s[1024];
    int t = threadIdx.x;
    int gid = blockIdx.x * 1024 + t;
    int v = (gid < len) ? in[gid] : 0;
    int x = v;
    s[t] = x;
    __syncthreads();
    for (int d = 1; d < 1024; d <<= 1) {
        int y = (t >= d) ? s[t - d] : 0;
        __syncthreads();
        x += y;
        s[t] = x;
        __syncthreads();
    }
    if (gid < len) outp[gid] = x - v;
    if (t == 1023) partials[blockIdx.x] = x;
}

__global__ __launch_bounds__(256) void k_scan_addp(int* __restrict__ data,
                                                   const int* __restrict__ partials, int len) {
    __shared__ int red[256];
    int tid = threadIdx.x;
    int K = blockIdx.x >> 2;          // number of preceding 1024-segments
    int s = 0;
    for (int t = tid; t < K; t += 256) s += partials[t];
    red[tid] = s;
    __syncthreads();
    for (int d = 128; d > 0; d >>= 1) {
        if (tid < d) red[tid] += red[tid + d];
        __syncthreads();
    }
    int gid = blockIdx.x * 256 + tid;
    if (gid < len) data[gid] += red[0];
}

// ---------------- K4: bucket-grouped COO scatter (LDS cursors, 1024 thr) ----------------
// 512-node buckets: per-block bucket runs ~42 edges (~336 B) -> minimal line amplification.

__global__ __launch_bounds__(1024) void k_scatter(const int* __restrict__ src,
                                                  const int* __restrict__ dst,
                                                  const int* __restrict__ tableT,
                                                  int2* __restrict__ bed,
                                                  int nA, int nbuck, int e) {
    __shared__ int cur[256];
    int blk = blockIdx.x, tid = threadIdx.x;
    for (int k = tid; k < nbuck; k += 1024)
        cur[k] = tableT[(size_t)k * nA + blk];
    __syncthreads();
    int base = blk * CHUNK;
    if (base + CHUNK <= e) {
        const int4* s4 = (const int4*)(src + base);
        const int4* d4 = (const int4*)(dst + base);
#pragma unroll
        for (int t = 0; t < CHUNK / 4096; ++t) {
            int4 s = s4[t * 1024 + tid];
            int4 d = d4[t * 1024 + tid];
            int p0 = atomicAdd(&cur[d.x >> BBITS], 1); bed[p0] = make_int2(s.x, d.x);
            int p1 = atomicAdd(&cur[d.y >> BBITS], 1); bed[p1] = make_int2(s.y, d.y);
            int p2 = atomicAdd(&cur[d.z >> BBITS], 1); bed[p2] = make_int2(s.z, d.z);
            int p3 = atomicAdd(&cur[d.w >> BBITS], 1); bed[p3] = make_int2(s.w, d.w);
        }
    } else {
        for (int i = base + tid; i < e; i += 1024) {
            int d = dst[i];
            int p = atomicAdd(&cur[d >> BBITS], 1);
            bed[p] = make_int2(src[i], d);
        }
    }
}

// ---------------- GEMM body: C[n,128](f16) = (A @ W) [* dinv[row] if SCALE] ----------------

template <bool AF32, bool SCALE>
__device__ __forceinline__ void gemm_body(int bid, int tid, char* smem,
                                          const void* __restrict__ Av,
                                          const _Float16* __restrict__ pW,
                                          const float* __restrict__ dinv,
                                          uint4* __restrict__ C, int n) {
    uint4* sW = (uint4*)smem;
    {
        const uint4* gW = (const uint4*)pW;
#pragma unroll
        for (int i = 0; i < 8; ++i) sW[tid + 256 * i] = gW[tid + 256 * i];
    }
    __syncthreads();

    int wave = tid >> 6, lane = tid & 63;
    int quad = lane >> 4, l16 = lane & 15;
    int row0 = bid * 64 + wave * 16;
    int arow = row0 + l16;
    int arowc = (arow < n) ? arow : (n - 1);

    half8 af[4];
    if (AF32) {
        const float* A = (const float*)Av + (size_t)arowc * 128 + quad * 8;
#pragma unroll
        for (int kc = 0; kc < 4; ++kc) {
            float4 lo = *(const float4*)(A + kc * 32);
            float4 hi = *(const float4*)(A + kc * 32 + 4);
            half8 h;
            h[0] = (_Float16)lo.x; h[1] = (_Float16)lo.y;
            h[2] = (_Float16)lo.z; h[3] = (_Float16)lo.w;
            h[4] = (_Float16)hi.x; h[5] = (_Float16)hi.y;
            h[6] = (_Float16)hi.z; h[7] = (_Float16)hi.w;
            af[kc] = h;
        }
    } else {
        const _Float16* A = (const _Float16*)Av + (size_t)arowc * 128 + quad * 8;
#pragma unroll
        for (int kc = 0; kc < 4; ++kc)
            af[kc] = *(const half8*)(A + kc * 32);
    }

    f32x4 acc[8];
#pragma unroll
    for (int ct = 0; ct < 8; ++ct) acc[ct] = (f32x4){0.f, 0.f, 0.f, 0.f};

#pragma unroll
    for (int kc = 0; kc < 4; ++kc) {
#pragma unroll
        for (int ct = 0; ct < 8; ++ct) {
            half8 bf = *(half8*)&sW[(kc * 8 + ct) * 64 + lane];
            acc[ct] = __builtin_amdgcn_mfma_f32_16x16x32_f16(af[kc], bf, acc[ct], 0, 0, 0);
        }
    }

    __syncthreads();

    _Float16* eb = (_Float16*)smem + wave * 16 * 136;   // 136 halfs = 272 B row stride
    float dv[4];
#pragma unroll
    for (int r = 0; r < 4; ++r) {
        if (SCALE) {
            int rr = row0 + quad * 4 + r;
            dv[r] = dinv[(rr < n) ? rr : (n - 1)];
        } else dv[r] = 1.f;
    }
#pragma unroll
    for (int ct = 0; ct < 8; ++ct)
#pragma unroll
        for (int r = 0; r < 4; ++r)
            eb[(quad * 4 + r) * 136 + ct * 16 + l16] =
                (_Float16)(SCALE ? acc[ct][r] * dv[r] : acc[ct][r]);

#pragma unroll
    for (int i = 0; i < 4; ++i) {
        int linear = i * 64 + lane;
        int r = linear >> 4, c = linear & 15;
        uint4 v = *(uint4*)((char*)eb + r * 272 + c * 16);
        int row = row0 + r;
        if (row < n) C[(size_t)row * 16 + c] = v;
    }
}

__global__ __launch_bounds__(256) void k_gemm_mfma(const void* __restrict__ Av,
                                                   const _Float16* __restrict__ pW,
                                                   const float* __restrict__ dinv,
                                                   uint4* __restrict__ C, int n) {
    __shared__ char smem[32768];
    gemm_body<false, true>(blockIdx.x, threadIdx.x, smem, Av, pW, dinv, C, n);
}

// ---------------- K5: per-bucket rank/offsets/er/dinv (512 nodes/bucket) ∥ GEMM1 ----------
// er base for bucket b = bedStart[b] + 4096*b (pad slack <= 512*7 < 4096).
// offs2[node] = {start, end}; er stores BYTE offsets (src*256). dinv computed here.

__global__ __launch_bounds__(256) void k_rank_gemm1(const int2* __restrict__ bed,
                                                    const int* __restrict__ tableT,
                                                    int2* __restrict__ offs2,
                                                    int* __restrict__ er,
                                                    float* __restrict__ dinv,
                                                    unsigned int* __restrict__ pad0,
                                                    const float* __restrict__ x,
                                                    const _Float16* __restrict__ pW,
                                                    uint4* __restrict__ C,
                                                    int nA, int nbuck, int n, int e) {
    __shared__ char smem[32768];
    int tid = threadIdx.x;
    int b = blockIdx.x;
    if (b >= nbuck) {                        // layer-1 GEMM from f32 x (dinv-free, unscaled)
        gemm_body<true, false>(b - nbuck, tid, smem, x, pW, nullptr, C, n);
        return;
    }
    int* lcnt = (int*)smem;                  // [512]
    int* loff = lcnt + 512;                  // [512]
    int* s    = loff + 512;                  // [256]
    if (b == 0) {
        if (tid < 64) pad0[tid] = 0u;        // zero 256 B pad row of buf0
        if (tid == 0) dinv[n] = 0.f;         // dummy-row scale (layer-1 SRC_SCALE path)
    }
    for (int k = tid; k < 512; k += 256) lcnt[k] = 0;
    __syncthreads();
    int start = tableT[(size_t)b * nA];
    int end = (b + 1 < nbuck) ? tableT[(size_t)(b + 1) * nA] : e;
    // pass 1: per-node counts
    for (int i = start + tid; i < end; i += 256)
        atomicAdd(&lcnt[bed[i].y & 511], 1);
    __syncthreads();
    // padded scan over 512 entries, 2 per thread
    int t2 = tid * 2;
    int c0 = lcnt[t2], c1 = lcnt[t2 + 1];
    int p0 = (c0 + 7) & ~7, p1 = (c1 + 7) & ~7;
    int xsum = p0 + p1;
    s[tid] = xsum;
    __syncthreads();
    for (int d = 1; d < 256; d <<= 1) {
        int y = (tid >= d) ? s[tid - d] : 0;
        __syncthreads();
        xsum += y;
        s[tid] = xsum;
        __syncthreads();
    }
    int ebase = start + (b << 12);
    int base0 = xsum - p0 - p1;              // exclusive padded offset of node t2
    loff[t2] = base0;
    loff[t2 + 1] = base0 + p0;
    {
        int node = (b << BBITS) + t2;
        if (node < n) {
            int o = ebase + base0;
            offs2[node] = make_int2(o, o + p0);
            dinv[node] = rsqrtf((float)(c0 + 1));
            for (int j = c0; j < p0; ++j) er[o + j] = n << 8;   // dummy zero-row
        }
        node = (b << BBITS) + t2 + 1;
        if (node < n) {
            int o = ebase + base0 + p0;
            offs2[node] = make_int2(o, o + p1);
            dinv[node] = rsqrtf((float)(c1 + 1));
            for (int j = c1; j < p1; ++j) er[o + j] = n << 8;
        }
    }
    __syncthreads();
    for (int k = tid; k < 512; k += 256) lcnt[k] = 0;   // reuse as rank cursors
    __syncthreads();
    // pass 2: place (bed window is L2-hot; er window ~fits L2 -> full-line writebacks)
    for (int i = start + tid; i < end; i += 256) {
        int2 q = bed[i];
        int l = q.y & 511;
        int r = atomicAdd(&lcnt[l], 1);
        er[ebase + loff[l] + r] = q.x << 8;             // BYTE offsets (src*256)
    }
}

// ---------------- fma_mix accumulate ----------------
// uint4 = 8 halfs: q.x -> f0,f1 | q.y -> f2,f3 | q.z -> f4,f5 | q.w -> f6,f7

__device__ __forceinline__ void acc_row4(float4& aL, float4& aH, uint4 q) {
    asm("v_fma_mix_f32 %0, %1, 1.0, %0 op_sel:[0,0,0] op_sel_hi:[1,0,0]" : "+v"(aL.x) : "v"(q.x));
    asm("v_fma_mix_f32 %0, %1, 1.0, %0 op_sel:[1,0,0] op_sel_hi:[1,0,0]" : "+v"(aL.y) : "v"(q.x));
    asm("v_fma_mix_f32 %0, %1, 1.0, %0 op_sel:[0,0,0] op_sel_hi:[1,0,0]" : "+v"(aL.z) : "v"(q.y));
    asm("v_fma_mix_f32 %0, %1, 1.0, %0 op_sel:[1,0,0] op_sel_hi:[1,0,0]" : "+v"(aL.w) : "v"(q.y));
    asm("v_fma_mix_f32 %0, %1, 1.0, %0 op_sel:[0,0,0] op_sel_hi:[1,0,0]" : "+v"(aH.x) : "v"(q.z));
    asm("v_fma_mix_f32 %0, %1, 1.0, %0 op_sel:[1,0,0] op_sel_hi:[1,0,0]" : "+v"(aH.y) : "v"(q.z));
    asm("v_fma_mix_f32 %0, %1, 1.0, %0 op_sel:[0,0,0] op_sel_hi:[1,0,0]" : "+v"(aH.z) : "v"(q.w));
    asm("v_fma_mix_f32 %0, %1, 1.0, %0 op_sel:[1,0,0] op_sel_hi:[1,0,0]" : "+v"(aH.w) : "v"(q.w));
}

__device__ __forceinline__ void acc_row4s(float4& aL, float4& aH, uint4 q, float s) {
    asm("v_fma_mix_f32 %0, %1, %2, %0 op_sel:[0,0,0] op_sel_hi:[1,0,0]" : "+v"(aL.x) : "v"(q.x), "v"(s));
    asm("v_fma_mix_f32 %0, %1, %2, %0 op_sel:[1,0,0] op_sel_hi:[1,0,0]" : "+v"(aL.y) : "v"(q.x), "v"(s));
    asm("v_fma_mix_f32 %0, %1, %2, %0 op_sel:[0,0,0] op_sel_hi:[1,0,0]" : "+v"(aL.z) : "v"(q.y), "v"(s));
    asm("v_fma_mix_f32 %0, %1, %2, %0 op_sel:[1,0,0] op_sel_hi:[1,0,0]" : "+v"(aL.w) : "v"(q.y), "v"(s));
    asm("v_fma_mix_f32 %0, %1, %2, %0 op_sel:[0,0,0] op_sel_hi:[1,0,0]" : "+v"(aH.x) : "v"(q.z), "v"(s));
    asm("v_fma_mix_f32 %0, %1, %2, %0 op_sel:[1,0,0] op_sel_hi:[1,0,0]" : "+v"(aH.y) : "v"(q.z), "v"(s));
    asm("v_fma_mix_f32 %0, %1, %2, %0 op_sel:[0,0,0] op_sel_hi:[1,0,0]" : "+v"(aH.z) : "v"(q.w), "v"(s));
    asm("v_fma_mix_f32 %0, %1, %2, %0 op_sel:[1,0,0] op_sel_hi:[1,0,0]" : "+v"(aH.w) : "v"(q.w), "v"(s));
}

// ---------------- CSR aggregation + bias + ReLU + BN (+ optional classifier) ----------------
// 16 lanes/node, uint4 gathers (R5-verified shape, VGPR ~36, occ ~70%).
// SRC_SCALE: source rows unscaled; multiply dinv[src] in fma_mix (layer 1 only).

template <bool FUSE_CLS, bool SRC_SCALE>
__global__ __launch_bounds__(256) void k_aggregate(const uint4* __restrict__ Ah,
                                                   const int2* __restrict__ offs2,
                                                   const int* __restrict__ er,
                                                   const float* __restrict__ dinv,
                                                   const float* __restrict__ bias,
                                                   const float* __restrict__ g,
                                                   const float* __restrict__ be,
                                                   const float* __restrict__ rm,
                                                   const float* __restrict__ rv,
                                                   uint4* __restrict__ Hout,
                                                   const float* __restrict__ Wc,
                                                   const float* __restrict__ bc,
                                                   float* __restrict__ out, int n) {
    int lane = threadIdx.x & 15;
    int node = blockIdx.x * 16 + (threadIdx.x >> 4);
    if (node >= n) return;

    const char* AhB = (const char*)Ah;
    unsigned int l16b = (unsigned int)lane * 16u;

    float di = dinv[node];
    float4 aL = f4zero(), aH = f4zero();
    {
        uint4 qs = *(const uint4*)(AhB + (((unsigned int)node << 8) + l16b));
        if (SRC_SCALE) acc_row4s(aL, aH, qs, di);
        else           acc_row4(aL, aH, qs);
    }

    int2 offc = offs2[node];
    for (int e = offc.x; e < offc.y; e += 8) {
        int4 ra = *(const int4*)(er + e);
        int4 rb = *(const int4*)(er + e + 4);
        uint4 v0 = *(const uint4*)(AhB + ((unsigned int)ra.x + l16b));
        uint4 v1 = *(const uint4*)(AhB + ((unsigned int)ra.y + l16b));
        uint4 v2 = *(const uint4*)(AhB + ((unsigned int)ra.z + l16b));
        uint4 v3 = *(const uint4*)(AhB + ((unsigned int)ra.w + l16b));
        uint4 v4 = *(const uint4*)(AhB + ((unsigned int)rb.x + l16b));
        uint4 v5 = *(const uint4*)(AhB + ((unsigned int)rb.y + l16b));
        uint4 v6 = *(const uint4*)(AhB + ((unsigned int)rb.z + l16b));
        uint4 v7 = *(const uint4*)(AhB + ((unsigned int)rb.w + l16b));
        if (SRC_SCALE) {
            float d0 = dinv[(unsigned int)ra.x >> 8];
            float d1 = dinv[(unsigned int)ra.y >> 8];
            float d2 = dinv[(unsigned int)ra.z >> 8];
            float d3 = dinv[(unsigned int)ra.w >> 8];
            float d4 = dinv[(unsigned int)rb.x >> 8];
            float d5 = dinv[(unsigned int)rb.y >> 8];
            float d6 = dinv[(unsigned int)rb.z >> 8];
            float d7 = dinv[(unsigned int)rb.w >> 8];
            acc_row4s(aL, aH, v0, d0); acc_row4s(aL, aH, v1, d1);
            acc_row4s(aL, aH, v2, d2); acc_row4s(aL, aH, v3, d3);
            acc_row4s(aL, aH, v4, d4); acc_row4s(aL, aH, v5, d5);
            acc_row4s(aL, aH, v6, d6); acc_row4s(aL, aH, v7, d7);
        } else {
            acc_row4(aL, aH, v0); acc_row4(aL, aH, v1); acc_row4(aL, aH, v2); acc_row4(aL, aH, v3);
            acc_row4(aL, aH, v4); acc_row4(aL, aH, v5); acc_row4(aL, aH, v6); acc_row4(aL, aH, v7);
        }
    }

    aL.x *= di; aL.y *= di; aL.z *= di; aL.w *= di;
    aH.x *= di; aH.y *= di; aH.z *= di; aH.w *= di;

    // lane covers features [8*lane, 8*lane+8) -> float4 indices 2*lane, 2*lane+1
    float4 bL  = ((const float4*)bias)[2 * lane], bH  = ((const float4*)bias)[2 * lane + 1];
    float4 gL  = ((const float4*)g)[2 * lane],    gH  = ((const float4*)g)[2 * lane + 1];
    float4 beL = ((const float4*)be)[2 * lane],   beH = ((const float4*)be)[2 * lane + 1];
    float4 rmL = ((const float4*)rm)[2 * lane],   rmH = ((const float4*)rm)[2 * lane + 1];
    float4 rvL = ((const float4*)rv)[2 * lane],   rvH = ((const float4*)rv)[2 * lane + 1];

    float4 oL, oH;
    float v;
    v = fmaxf(aL.x + bL.x, 0.f); oL.x = (v - rmL.x) * rsqrtf(rvL.x + BN_EPS) * gL.x + beL.x;
    v = fmaxf(aL.y + bL.y, 0.f); oL.y = (v - rmL.y) * rsqrtf(rvL.y + BN_EPS) * gL.y + beL.y;
    v = fmaxf(aL.z + bL.z, 0.f); oL.z = (v - rmL.z) * rsqrtf(rvL.z + BN_EPS) * gL.z + beL.z;
    v = fmaxf(aL.w + bL.w, 0.f); oL.w = (v - rmL.w) * rsqrtf(rvL.w + BN_EPS) * gL.w + beL.w;
    v = fmaxf(aH.x + bH.x, 0.f); oH.x = (v - rmH.x) * rsqrtf(rvH.x + BN_EPS) * gH.x + beH.x;
    v = fmaxf(aH.y + bH.y, 0.f); oH.y = (v - rmH.y) * rsqrtf(rvH.y + BN_EPS) * gH.y + beH.y;
    v = fmaxf(aH.z + bH.z, 0.f); oH.z = (v - rmH.z) * rsqrtf(rvH.z + BN_EPS) * gH.z + beH.z;
    v = fmaxf(aH.w + bH.w, 0.f); oH.w = (v - rmH.w) * rsqrtf(rvH.w + BN_EPS) * gH.w + beH.w;

    if (!FUSE_CLS) {
        __half2 p0 = __floats2half2_rn(oL.x, oL.y);
        __half2 p1 = __floats2half2_rn(oL.z, oL.w);
        __half2 p2 = __floats2half2_rn(oH.x, oH.y);
        __half2 p3 = __floats2half2_rn(oH.z, oH.w);
        uint4 u;
        u.x = *(unsigned int*)&p0;
        u.y = *(unsigned int*)&p1;
        u.z = *(unsigned int*)&p2;
        u.w = *(unsigned int*)&p3;
        Hout[(size_t)node * 16 + lane] = u;
    } else {
        const float4* Wv = (const float4*)Wc;   // Wc[f][2]: float4 i = features 2i,2i+1
        float4 w0 = Wv[4 * lane];
        float4 w1 = Wv[4 * lane + 1];
        float4 w2 = Wv[4 * lane + 2];
        float4 w3 = Wv[4 * lane + 3];
        float p0 = oL.x * w0.x + oL.y * w0.z + oL.z * w1.x + oL.w * w1.z
                 + oH.x * w2.x + oH.y * w2.z + oH.z * w3.x + oH.w * w3.z;
        float p1 = oL.x * w0.y + oL.y * w0.w + oL.z * w1.y + oL.w * w1.w
                 + oH.x * w2.y + oH.y * w2.w + oH.z * w3.y + oH.w * w3.w;
#pragma unroll
        for (int d = 8; d >= 1; d >>= 1) {
            p0 += __shfl_down(p0, d, 16);
            p1 += __shfl_down(p1, d, 16);
        }
        if (lane == 0) {
            out[node * 2 + 0] = p0 + bc[0];
            out[node * 2 + 1] = p1 + bc[1];
        }
    }
}

// ---------------- launch ----------------

extern "C" void kernel_launch(void* const* d_in, const int* in_sizes, int n_in,
                              void* d_out, int out_size, void* d_ws, size_t ws_size,
                              hipStream_t stream) {
    const float* x   = (const float*)d_in[0];
    const int*   ei  = (const int*)d_in[1];
    const float* W1  = (const float*)d_in[2];
    const float* b1  = (const float*)d_in[3];
    const float* W2  = (const float*)d_in[4];
    const float* b2  = (const float*)d_in[5];
    const float* W3  = (const float*)d_in[6];
    const float* b3  = (const float*)d_in[7];
    const float* g1  = (const float*)d_in[8];
    const float* be1 = (const float*)d_in[9];
    const float* rm1 = (const float*)d_in[10];
    const float* rv1 = (const float*)d_in[11];
    const float* g2  = (const float*)d_in[12];
    const float* be2 = (const float*)d_in[13];
    const float* rm2 = (const float*)d_in[14];
    const float* rv2 = (const float*)d_in[15];
    const float* g3  = (const float*)d_in[16];
    const float* be3 = (const float*)d_in[17];
    const float* rm3 = (const float*)d_in[18];
    const float* rv3 = (const float*)d_in[19];
    const float* Wc  = (const float*)d_in[20];
    const float* bc  = (const float*)d_in[21];
    float* out = (float*)d_out;

    int n = in_sizes[0] / 128;
    int e = in_sizes[1] / 2;
    const int* src = ei;
    const int* dst = ei + e;

    char* ws = (char*)d_ws;
    size_t off = 0;
    auto alloc = [&](size_t bytes) -> char* {
        char* p = ws + off;
        off += (bytes + 255) & ~(size_t)255;
        return p;
    };
    int nA    = (e + CHUNK - 1) / CHUNK;
    int nbuck = (n + (1 << BBITS) - 1) >> BBITS;
    int tlen  = nbuck * nA;
    int erCap = e + (nbuck << 12) + 64;

    char*      buf0     = (char*) alloc((size_t)(n + 1) * 256);   // gemm out (ping)
    char*      buf1     = (char*) alloc((size_t)(n + 1) * 256);   // agg out (pong); bed aliases
    float*     dinv     = (float*)alloc((size_t)(n + 1) * 4);
    int2*      offs2    = (int2*) alloc((size_t)n * 8);
    int*       tableT   = (int*)  alloc((size_t)(tlen + 1) * 4);
    int*       parts    = (int*)  alloc(8192);
    int*       er       = (int*)  alloc((size_t)erCap * 4);
    _Float16*  pW       = (_Float16*)alloc(3 * 16384 * 2);
    (void)ws_size; (void)n_in; (void)out_size;

    // bed aliases buf1 (dead until agg1 writes; consumed by k_rank_gemm1)
    int2* bed = (int2*)buf1;                         // e*8 = 12.8 MB < 25.6 MB

    int nbT   = (tlen + 1023) / 1024;
    int gT    = (tlen + 255) / 256;
    int gGemm = (n + 63) / 64;
    int gAgg  = (n + 15) / 16;

    k_pack_hist<<<6 + nA, 1024, 0, stream>>>(W1, W2, W3, pW, dst, tableT, nA, nbuck, e);
    k_scan_block<<<nbT, 1024, 0, stream>>>(tableT, tableT, parts, tlen);
    k_scan_addp<<<gT, 256, 0, stream>>>(tableT, parts, tlen);
    k_scatter<<<nA, 1024, 0, stream>>>(src, dst, tableT, bed, nA, nbuck, e);
    // rank/finalize (196 blocks) ∥ layer-1 GEMM (1563 blocks, dinv-free)
    k_rank_gemm1<<<nbuck + gGemm, 256, 0, stream>>>(
        bed, tableT, offs2, er, dinv,
        (unsigned int*)(buf0 + (size_t)n * 256),
        x, pW, (uint4*)buf0, nA, nbuck, n, e);

    // layer 1: agg (buf0 unscaled -> buf1, SRC_SCALE)
    k_aggregate<false, true><<<gAgg, 256, 0, stream>>>(
        (const uint4*)buf0, offs2, er, dinv, b1, g1, be1, rm1, rv1,
        (uint4*)buf1, nullptr, nullptr, nullptr, n);
    // layer 2: gemm (buf1 -> buf0, ×dinv), agg (buf0 -> buf1)
    k_gemm_mfma<<<gGemm, 256, 0, stream>>>(buf1, pW + 16384, dinv, (uint4*)buf0, n);
    k_aggregate<false, false><<<gAgg, 256, 0, stream>>>(
        (const uint4*)buf0, offs2, er, dinv, b2, g2, be2, rm2, rv2,
        (uint4*)buf1, nullptr, nullptr, nullptr, n);
    // layer 3: gemm (buf1 -> buf0, ×dinv), agg + classifier (buf0 -> out)
    k_gemm_mfma<<<gGemm, 256, 0, stream>>>(buf1, pW + 32768, dinv, (uint4*)buf0, n);
    k_aggregate<true, false><<<gAgg, 256, 0, stream>>>(
        (const uint4*)buf0, offs2, er, dinv, b3, g3, be3, rm3, rv3,
        nullptr, Wc, bc, out, n);
}